// Round 2
// baseline (5918.425 us; speedup 1.0000x reference)
//
#include <hip/hip_runtime.h>
#include <hip/hip_bf16.h>

// CrossGRU round 7: persistent single-kernel GRU scan with device-wide barrier.
// r6 measured ~21.4us/step across 129 serial launches while per-CU pipe floors sum to
// ~6us: the cost was structural (launch+drain, per-launch LDS weight re-staging, cold
// cache latency). r7: ONE kernel, 256 blocks x 512 threads (1 block/CU forced by 126KB
// LDS -> co-residency by construction, plain launch), waves 0-3 = layer0 step i,
// waves 4-7 = layer1 step i-1, both B slices staged to LDS ONCE, hand-rolled grid
// barrier (monotonic counter + agent fences for XCD L2 non-coherence) between steps.
// S1f written only at the final step.

#define HH  256
#define TT  128
#define INP 64
#define KH  8   // h-part kc count (256/32)

typedef float f32x4 __attribute__((ext_vector_type(4)));
typedef short bf16x8 __attribute__((ext_vector_type(8)));

#define MFMA(A,B,C) __builtin_amdgcn_mfma_f32_16x16x32_bf16((A),(B),(C),0,0,0)

__device__ __forceinline__ float bf2f(unsigned short s) {
    unsigned u = ((unsigned)s) << 16;
    float f; __builtin_memcpy(&f, &u, 4); return f;
}
__device__ __forceinline__ unsigned short f2bf(float f) {
    unsigned u; __builtin_memcpy(&u, &f, 4);
    unsigned r = (u + 0x7FFFu + ((u >> 16) & 1u)) >> 16;
    return (unsigned short)r;
}

// fragment-major index for element (row r, col k), K cols:
// idx = (r>>4)*(K*16) + (k>>5)*512 + ((k>>3)&3)*128 + (r&15)*8 + (k&7)

__global__ void pack_w(const float* __restrict__ Whh, const float* __restrict__ Wih,
                       int Kin, int Kw, unsigned short* __restrict__ FBhi,
                       unsigned short* __restrict__ FBlo, int total)
{
    int idx = blockIdx.x * 256 + threadIdx.x;
    if (idx >= total) return;
    int n = idx / Kw, k = idx - n * Kw;
    float v = (k < 256) ? Whh[n * 256 + k] : Wih[n * Kin + (k - 256)];
    int dst = (n >> 4) * (Kw * 16) + (k >> 5) * 512 + ((k >> 3) & 3) * 128 + (n & 15) * 8 + (k & 7);
    unsigned short h = f2bf(v);
    FBhi[dst] = h;
    FBlo[dst] = f2bf(v - bf2f(h));
}

__global__ void pack_x(const float* __restrict__ x, unsigned short* __restrict__ FXhi)
{
    int idx = blockIdx.x * 256 + threadIdx.x;  // 2048*128*64
    int k = idx & 63;
    int t = (idx >> 6) & 127;
    int m = idx >> 13;
    int dst = t * 131072 + (m >> 4) * 1024 + (k >> 5) * 512 + ((k >> 3) & 3) * 128 + (m & 15) * 8 + (k & 7);
    FXhi[dst] = f2bf(x[idx]);
}

// ---------------- B staging: global (frag-major, per-ntb slice) -> LDS ----------------
// LDS layout (shorts): Bhi[3][NKC*512]  then  Blo_h[3][KH*512]
template<int NKC, int STRIDE>
__device__ __forceinline__ void stage_Bs(const unsigned short* __restrict__ Bhi,
                                         const unsigned short* __restrict__ Blo,
                                         short* __restrict__ sB, int ntb, int tid)
{
    const int Kw16 = NKC * 512;
#pragma unroll 1
    for (int t = tid; t < 3 * NKC * 64; t += STRIDE) {
        const int g = t / (NKC * 64);
        const int r = t - g * (NKC * 64);
        *(bf16x8*)(sB + g * Kw16 + r * 8) =
            *(const bf16x8*)(Bhi + (g * 16 + ntb) * Kw16 + r * 8);
    }
#pragma unroll 1
    for (int t = tid; t < 3 * KH * 64; t += STRIDE) {
        const int g = t >> 9;
        const int r = t & 511;
        *(bf16x8*)(sB + 3 * Kw16 + g * (KH * 512) + r * 8) =
            *(const bf16x8*)(Blo + (g * 16 + ntb) * Kw16 + r * 8);
    }
}

// ---------------- GRU step core ----------------
// wave = 32 rows (2 m-tiles) x 16 ch (1 n-tile per gate), 3-term hi/lo MFMA.
// B_hi (all kc) and B_lo (kc<KH) from LDS; B_lo for x-part (kc>=KH) register-direct.
template<int NKC, bool LAY>
__device__ __forceinline__ void gru_core(
    const unsigned short* __restrict__ Ah_h, const unsigned short* __restrict__ Al_h,
    const unsigned short* __restrict__ Ah_x, const unsigned short* __restrict__ Al_x,
    const short* __restrict__ sB, const unsigned short* __restrict__ B_lo,
    int mt0, int ntb, int lane,
    f32x4 (&ar)[2], f32x4 (&az)[2], f32x4 (&anh)[2], f32x4 (&anx)[2])
{
    const int Kw16 = NKC * 512;            // Kw*16
    const int xs = LAY ? 4096 : 1024;      // x-source per-m-tile stride
    const int lo8 = lane * 8;
    const unsigned short* blg[3];
#pragma unroll
    for (int g = 0; g < 3; ++g)
        blg[g] = B_lo + (g * 16 + ntb) * Kw16 + lo8;
    const short* sH = sB + lo8;
    const short* sL = sB + 3 * Kw16 + lo8;

    bf16x8 cA[2][2], cB[3][2], nA[2][2], nB[3][2];

    auto ldA = [&](int kc, bf16x8 (&A)[2][2]) {
        if (kc < KH) {
#pragma unroll
            for (int mt = 0; mt < 2; ++mt) {
                A[mt][0] = *(const bf16x8*)(Ah_h + (mt0 + mt) * 4096 + kc * 512 + lo8);
                A[mt][1] = *(const bf16x8*)(Al_h + (mt0 + mt) * 4096 + kc * 512 + lo8);
            }
        } else {
#pragma unroll
            for (int mt = 0; mt < 2; ++mt) {
                A[mt][0] = *(const bf16x8*)(Ah_x + (mt0 + mt) * xs + (kc - KH) * 512 + lo8);
                if (LAY)
                    A[mt][1] = *(const bf16x8*)(Al_x + (mt0 + mt) * xs + (kc - KH) * 512 + lo8);
            }
        }
    };
    auto ldB = [&](int kc, bf16x8 (&B)[3][2]) {
#pragma unroll
        for (int g = 0; g < 3; ++g) {
            B[g][0] = *(const bf16x8*)(sH + g * Kw16 + kc * 512);
            B[g][1] = (kc < KH)
                ? *(const bf16x8*)(sL + g * (KH * 512) + kc * 512)
                : *(const bf16x8*)(blg[g] + kc * 512);
        }
    };

    ldA(0, cA); ldB(0, cB);
#pragma unroll
    for (int kc = 0; kc < NKC; ++kc) {
        if (kc + 1 < NKC) { ldA(kc + 1, nA); ldB(kc + 1, nB); }
        const bool hp = (kc < KH);
        const bool a3 = LAY || hp;     // 3rd (a_lo) term availability
#pragma unroll
        for (int mt = 0; mt < 2; ++mt) {
            ar[mt] = MFMA(cA[mt][0], cB[0][0], ar[mt]);
            ar[mt] = MFMA(cA[mt][0], cB[0][1], ar[mt]);
            if (a3) ar[mt] = MFMA(cA[mt][1], cB[0][0], ar[mt]);
            az[mt] = MFMA(cA[mt][0], cB[1][0], az[mt]);
            az[mt] = MFMA(cA[mt][0], cB[1][1], az[mt]);
            if (a3) az[mt] = MFMA(cA[mt][1], cB[1][0], az[mt]);
            if (hp) {
                anh[mt] = MFMA(cA[mt][0], cB[2][0], anh[mt]);
                anh[mt] = MFMA(cA[mt][0], cB[2][1], anh[mt]);
                if (a3) anh[mt] = MFMA(cA[mt][1], cB[2][0], anh[mt]);
            } else {
                anx[mt] = MFMA(cA[mt][0], cB[2][0], anx[mt]);
                anx[mt] = MFMA(cA[mt][0], cB[2][1], anx[mt]);
                if (a3) anx[mt] = MFMA(cA[mt][1], cB[2][0], anx[mt]);
            }
        }
#pragma unroll
        for (int mt = 0; mt < 2; ++mt) { cA[mt][0] = nA[mt][0]; cA[mt][1] = nA[mt][1]; }
#pragma unroll
        for (int g = 0; g < 3; ++g) { cB[g][0] = nB[g][0]; cB[g][1] = nB[g][1]; }
    }
}

// Device-wide barrier: monotonic counter, one atomic per block.
// Release: __syncthreads (drains vmcnt -> stores in L2) + agent fence (L2 writeback).
// Acquire: agent fence after spin (L1/L2 invalidate) -> fresh cross-XCD reads.
__device__ __forceinline__ void grid_bar(unsigned* cnt, unsigned need)
{
    __syncthreads();
    asm volatile("" ::: "memory");
    if (threadIdx.x == 0) {
        __threadfence();
        __hip_atomic_fetch_add(cnt, 1u, __ATOMIC_RELEASE, __HIP_MEMORY_SCOPE_AGENT);
        while (__hip_atomic_load(cnt, __ATOMIC_RELAXED, __HIP_MEMORY_SCOPE_AGENT) < need)
            __builtin_amdgcn_s_sleep(1);
        __threadfence();
    }
    asm volatile("" ::: "memory");
    __syncthreads();
}

// Persistent scan: 256 blocks x 512 threads. Block b: mb=b>>4 (128 rows), cb=b&15 (16 ch).
// Waves 0-3: layer0 step i; waves 4-7: layer1 step i-1. 126KB LDS forces 1 block/CU,
// grid==CU count -> all blocks co-resident (LDS-limited), plain launch is barrier-safe.
// NOTE: H pointers intentionally NOT __restrict__ (other blocks write them between
// barriers; restrict would license load hoisting across iterations).
__global__ __launch_bounds__(512, 2) void gru_scan(
    unsigned short* H0hiA, unsigned short* H0loA,
    unsigned short* H0hiB, unsigned short* H0loB,
    unsigned short* H1hiA, unsigned short* H1loA,
    unsigned short* H1hiB, unsigned short* H1loB,
    const unsigned short* __restrict__ FXhi,
    const unsigned short* __restrict__ FB0hi, const unsigned short* __restrict__ FB0lo,
    const unsigned short* __restrict__ FB1hi, const unsigned short* __restrict__ FB1lo,
    const float* __restrict__ bih0, const float* __restrict__ bhh0,
    const float* __restrict__ bih1, const float* __restrict__ bhh1,
    float* __restrict__ S1f, unsigned* bar)
{
    const int bid = blockIdx.x;       // 256
    const int mb = bid >> 4, cb = bid & 15;
    const int tid = threadIdx.x;
    const int w = tid >> 6, lane = tid & 63;
    const int lay = w >> 2, wl = w & 3;
    const int l15 = lane & 15, q = lane >> 4;
    const int mt0 = mb * 8 + wl * 2;  // first 16-row tile (of 128)
    const int ntb = cb;               // 16-ch tile within gate

    // sB1: Bhi[3][16*512] + Blo_h[3][8*512] = 36864 shorts (72KB)
    // sB0: Bhi[3][10*512] + Blo_h[3][8*512] = 27648 shorts (54KB)
    __shared__ __align__(16) short sB[64512];
    short* sB1 = sB;
    short* sB0 = sB + 36864;
    stage_Bs<16, 512>(FB1hi, FB1lo, sB1, cb, tid);
    stage_Bs<10, 512>(FB0hi, FB0lo, sB0, cb, tid);
    __syncthreads();

    // per-thread epilogue constants (hoisted out of the scan loop)
    const float* bih = lay ? bih1 : bih0;
    const float* bhh = lay ? bhh1 : bhh0;
    const int c = (ntb << 4) + l15;   // channel 0..255
    const float brb = bih[c] + bhh[c];
    const float bzb = bih[256 + c] + bhh[256 + c];
    const float bni = bih[512 + c];
    const float bnh = bhh[512 + c];
    const int cfr = (c >> 5) * 512 + ((c >> 3) & 3) * 128 + (c & 7);

    unsigned need = 256;
    for (int i = 0; i <= TT; ++i) {
        const int p = i & 1;
        const unsigned short* H0r_hi = p ? H0hiB : H0hiA;
        const unsigned short* H0r_lo = p ? H0loB : H0loA;
        unsigned short*       H0w_hi = p ? H0hiA : H0hiB;
        unsigned short*       H0w_lo = p ? H0loA : H0loB;
        const unsigned short* H1r_hi = p ? H1hiB : H1hiA;
        const unsigned short* H1r_lo = p ? H1loB : H1loA;
        unsigned short*       H1w_hi = p ? H1hiA : H1hiB;
        unsigned short*       H1w_lo = p ? H1loA : H1loB;

        const bool active = lay ? (i >= 1) : (i < TT);
        if (active) {
            f32x4 ar[2], az[2], anh[2], anx[2];
#pragma unroll
            for (int j = 0; j < 2; ++j) {
                ar[j] = (f32x4){0.f,0.f,0.f,0.f}; az[j] = (f32x4){0.f,0.f,0.f,0.f};
                anh[j] = (f32x4){0.f,0.f,0.f,0.f}; anx[j] = (f32x4){0.f,0.f,0.f,0.f};
            }
            if (lay) {
                gru_core<16, true>(H1r_hi, H1r_lo, H0r_hi, H0r_lo, sB1, FB1lo,
                                   mt0, ntb, lane, ar, az, anh, anx);
            } else {
                gru_core<10, false>(H0r_hi, H0r_lo, FXhi + i * 131072,
                                    (const unsigned short*)0, sB0, FB0lo,
                                    mt0, ntb, lane, ar, az, anh, anx);
            }

            const unsigned short* Ahi_h = lay ? H1r_hi : H0r_hi;
            const unsigned short* Alo_h = lay ? H1r_lo : H0r_lo;
            unsigned short* Whi = lay ? H1w_hi : H0w_hi;
            unsigned short* Wlo = lay ? H1w_lo : H0w_lo;

#pragma unroll
            for (int mt = 0; mt < 2; ++mt) {
                const int mtg = mt0 + mt;
                const int fbase = mtg * 4096 + cfr;
#pragma unroll
                for (int rg = 0; rg < 4; ++rg) {
                    const int mi = q * 4 + rg;
                    const int fidx = fbase + mi * 8;
                    const float ho = bf2f(Ahi_h[fidx]) + bf2f(Alo_h[fidx]);
                    const float rr = 1.f / (1.f + expf(-(ar[mt][rg] + brb)));
                    const float zz = 1.f / (1.f + expf(-(az[mt][rg] + bzb)));
                    const float nn = tanhf(anx[mt][rg] + bni + rr * (anh[mt][rg] + bnh));
                    const float hn = (1.f - zz) * nn + zz * ho;
                    const unsigned short hb = f2bf(hn);
                    Whi[fidx] = hb;
                    Wlo[fidx] = f2bf(hn - bf2f(hb));
                    if (lay && i == TT) S1f[(mtg * 16 + mi) * 256 + c] = hn;
                }
            }
        }
        grid_bar(bar, need);
        need += 256;
    }
}

// ---------------- epilogue ----------------

__global__ __launch_bounds__(256) void proj_gemm(const float* __restrict__ S,
    const float* __restrict__ Wk, const float* __restrict__ bk,
    const float* __restrict__ Wv, const float* __restrict__ bv,
    const float* __restrict__ Wq, const float* __restrict__ bq,
    float* __restrict__ ok, float* __restrict__ ov, float* __restrict__ oq)
{
    __shared__ float sT[256][65];
    const int bid = blockIdx.x;            // 192 = 3p * 2h * 32lt
    const int p = bid >> 6;
    const int h = (bid >> 5) & 1;
    const int l0 = (bid & 31) * 64;
    const int tid = threadIdx.x;
    const float* W = (p == 0) ? Wk : ((p == 1) ? Wv : Wq);
    const float* b = (p == 0) ? bk : ((p == 1) ? bv : bq);
    float* o = (p == 0) ? ok : ((p == 1) ? ov : oq);

    for (int e = tid; e < 64 * 256; e += 256) {
        int k = e & 255, l = e >> 8;
        sT[k][l] = S[(l0 + l) * 256 + k];
    }
    __syncthreads();

    const int dg = tid & 15, lg = tid >> 4;
    const int d0 = dg * 8;
    const float* Wp = W + h * 32768 + d0;
    float acc[4][8];
#pragma unroll
    for (int i = 0; i < 4; ++i)
#pragma unroll
        for (int j = 0; j < 8; ++j) acc[i][j] = 0.f;

    for (int k = 0; k < 256; ++k) {
        f32x4 sv = *(const f32x4*)&sT[k][lg * 4];
        f32x4 w0 = *(const f32x4*)(Wp + k * 128);
        f32x4 w1 = *(const f32x4*)(Wp + k * 128 + 4);
#pragma unroll
        for (int i = 0; i < 4; ++i) {
#pragma unroll
            for (int j = 0; j < 4; ++j) {
                acc[i][j]     += sv[i] * w0[j];
                acc[i][4 + j] += sv[i] * w1[j];
            }
        }
    }
#pragma unroll
    for (int i = 0; i < 4; ++i) {
        float* op = o + (h * 2048 + l0 + lg * 4 + i) * 128 + d0;
#pragma unroll
        for (int j = 0; j < 8; ++j) op[j] = acc[i][j] + b[h * 128 + d0 + j];
    }
}

__global__ void proj3_kernel(const float* __restrict__ A, int M,
    const float* __restrict__ Wk, const float* __restrict__ bk,
    const float* __restrict__ Wv, const float* __restrict__ bv,
    float* __restrict__ ok, float* __restrict__ ov)
{
    int idx = blockIdx.x * 256 + threadIdx.x;
    if (idx >= 2 * 2 * M * 128) return;
    int d = idx & 127;
    int rest = idx >> 7;
    int l = rest % M;
    int ph = rest / M;
    int h = ph & 1, p = ph >> 1;
    const float* W = (p == 0) ? Wk : Wv;
    const float* b = (p == 0) ? bk : bv;
    float* o = (p == 0) ? ok : ov;
    float accv = b[h * 128 + d];
    const float* a = A + l * 256;
    const float* wp = W + h * (256 * 128) + d;
    for (int j = 0; j < 256; ++j) accv += a[j] * wp[j * 128];
    o[(h * M + l) * 128 + d] = accv;
}

__global__ void projR_kernel(const float* __restrict__ R,
    const float* __restrict__ Wq, const float* __restrict__ bq,
    float* __restrict__ oq)
{
    int idx = blockIdx.x * 256 + threadIdx.x;
    if (idx >= 2 * 30 * 128) return;
    int d = idx & 127;
    int rest = idx >> 7;
    int l = rest % 30;
    int h = rest / 30;
    float a = bq[h * 128 + d];
    const float* r = R + l * 256;
    const float* wp = Wq + h * 32768 + d;
    for (int j = 0; j < 256; ++j) a += r[j] * wp[j * 128];
    oq[(h * 30 + l) * 128 + d] = a;
}

__global__ void scores1_kernel(const float* __restrict__ qhR, const float* __restrict__ kh,
                               float* __restrict__ s1)
{
    int idx = blockIdx.x * 256 + threadIdx.x;
    if (idx >= 2 * 30 * 2048) return;
    int k = idx & 2047;
    int rest = idx >> 11;
    int i = rest % 30;
    int h = rest / 30;
    const f32x4* qp = (const f32x4*)(qhR + (h * 30 + i) * 128);
    const f32x4* kp = (const f32x4*)(kh + (h * 2048 + k) * 128);
    float acc = 0.f;
    for (int dd = 0; dd < 32; ++dd) {
        f32x4 a = qp[dd], b = kp[dd];
        acc += a[0] * b[0] + a[1] * b[1] + a[2] * b[2] + a[3] * b[3];
    }
    s1[idx] = acc * 0.08838834764831845f;
}

__global__ void softmax1_kernel(float* __restrict__ s1)
{
    __shared__ float red[256];
    float* p = s1 + blockIdx.x * 2048;
    int tid = threadIdx.x;
    float mx = -1e30f;
    for (int k = tid; k < 2048; k += 256) mx = fmaxf(mx, p[k]);
    red[tid] = mx; __syncthreads();
    for (int s = 128; s > 0; s >>= 1) { if (tid < s) red[tid] = fmaxf(red[tid], red[tid + s]); __syncthreads(); }
    mx = red[0]; __syncthreads();
    float sum = 0.f;
    for (int k = tid; k < 2048; k += 256) { float e = expf(p[k] - mx); p[k] = e; sum += e; }
    red[tid] = sum; __syncthreads();
    for (int s = 128; s > 0; s >>= 1) { if (tid < s) red[tid] += red[tid + s]; __syncthreads(); }
    float inv = 1.f / red[0];
    for (int k = tid; k < 2048; k += 256) p[k] *= inv;
}

// split-K o1: 16 k-slices per output row, fp32 atomicAdd into zeroed Bm.
__global__ void o1_kernel(const float* __restrict__ p1, const float* __restrict__ vh,
                          float* __restrict__ Bm)
{
    int bid = blockIdx.x;            // 60 rows * 16 k-slices
    int row = bid >> 4;              // h*30+i
    int ks = bid & 15;
    int h = row / 30;
    int i = row % 30;
    int d = threadIdx.x;             // 128
    const float* pp = p1 + row * 2048 + ks * 128;
    const float* vp = vh + (h * 2048 + ks * 128) * 128 + d;
    float acc = 0.f;
    for (int k = 0; k < 128; ++k) acc += pp[k] * vp[k * 128];
    atomicAdd(&Bm[i * 256 + h * 128 + d], acc);
}

__global__ __launch_bounds__(256) void attn2_kernel(
    const float* __restrict__ qh2, const float* __restrict__ kh2, const float* __restrict__ vh2,
    const float* __restrict__ S, const float* __restrict__ Wg,
    const float* __restrict__ bg, float* __restrict__ Smix)
{
    __shared__ float ks[2 * 30 * 129];
    __shared__ float qred[256];
    __shared__ float ps[64];
    int l = blockIdx.x;
    int tid = threadIdx.x;
    for (int idx = tid; idx < 2 * 30 * 128; idx += 256) {
        int hh = idx / 3840; int rem = idx - hh * 3840;
        int j = rem >> 7; int d = rem & 127;
        ks[(hh * 30 + j) * 129 + d] = kh2[idx];
    }
    int h = tid >> 7, d = tid & 127;
    qred[tid] = qh2[(h * 2048 + l) * 128 + d];
    __syncthreads();
    int w = tid >> 6, lane = tid & 63;
    if (w < 2 && lane < 32) {
        float sc = -1e30f;
        if (lane < 30) {
            const float* qp = qred + w * 128;
            float a = 0.f;
            for (int dd = 0; dd < 128; ++dd) a += qp[dd] * ks[(w * 30 + lane) * 129 + dd];
            sc = a * 0.08838834764831845f;
        }
        float mx = sc;
        for (int m = 16; m > 0; m >>= 1) mx = fmaxf(mx, __shfl_xor(mx, m, 32));
        float e = (lane < 30) ? expf(sc - mx) : 0.f;
        float sm = e;
        for (int m = 16; m > 0; m >>= 1) sm += __shfl_xor(sm, m, 32);
        ps[w * 32 + lane] = e / sm;
    }
    __syncthreads();
    float o = 0.f;
    const float* vp = vh2 + h * 3840 + d;
    for (int j = 0; j < 30; ++j) o += ps[h * 32 + j] * vp[j * 128];
    float sl = S[l * 256 + tid];
    qred[tid] = sl * Wg[tid];
    __syncthreads();
    for (int s = 128; s > 0; s >>= 1) { if (tid < s) qred[tid] += qred[tid + s]; __syncthreads(); }
    float alpha = 1.f / (1.f + expf(-(qred[0] + bg[0])));
    Smix[l * 256 + tid] = alpha * o + (1.f - alpha) * sl;
}

__global__ void w1t_kernel(const float* __restrict__ W1, float* __restrict__ W1T)
{
    int idx = blockIdx.x * 256 + threadIdx.x;  // 65536
    int j = idx & 255, c = idx >> 8;
    W1T[j * 256 + c] = W1[c * 256 + j];
}

__global__ void mlp_kernel(const float* __restrict__ Smix, const float* __restrict__ W1T,
                           const float* __restrict__ b1, float* __restrict__ S2)
{
    int idx = blockIdx.x * 256 + threadIdx.x;  // l*256+c
    int c = idx & 255; int l = idx >> 8;
    const float* a = Smix + l * 256;
    float acc = b1[c];
    for (int j = 0; j < 256; ++j) acc += a[j] * W1T[j * 256 + c];
    float v = fmaxf(acc, 0.f);
    S2[idx] = v + a[c];
}

__global__ void y_kernel(const float* __restrict__ S2, const float* __restrict__ W2,
                         const float* __restrict__ b2, float* __restrict__ y)
{
    __shared__ float red[256];
    int l = blockIdx.x; int tid = threadIdx.x;
    red[tid] = S2[l * 256 + tid] * W2[tid];
    __syncthreads();
    for (int s = 128; s > 0; s >>= 1) { if (tid < s) red[tid] += red[tid + s]; __syncthreads(); }
    if (tid == 0) y[l] = red[0] + b2[0];
}

__global__ void norm_kernel(const float* __restrict__ y, float* __restrict__ out)
{
    __shared__ float r1[1024], r2[1024];
    int tid = threadIdx.x;
    float s1v = 0.f, s2v = 0.f;
    for (int idx = tid; idx < 2048; idx += 1024) { float v = y[idx]; s1v += v; s2v += v * v; }
    r1[tid] = s1v; r2[tid] = s2v; __syncthreads();
    for (int s = 512; s > 0; s >>= 1) {
        if (tid < s) { r1[tid] += r1[tid + s]; r2[tid] += r2[tid + s]; }
        __syncthreads();
    }
    float mean = r1[0] / 2048.f;
    float var = fmaxf((r2[0] - 2048.f * mean * mean) / 2047.f, 0.f);
    float inv = 1.f / (sqrtf(var) + 1e-8f);
    for (int idx = tid; idx < 2048; idx += 1024)
        out[idx] = (y[idx] - mean) * inv;
}

extern "C" void kernel_launch(void* const* d_in, const int* in_sizes, int n_in,
                              void* d_out, int out_size, void* d_ws, size_t ws_size,
                              hipStream_t stream)
{
    const float* x    = (const float*)d_in[0];
    const float* Wih0 = (const float*)d_in[1];
    const float* Whh0 = (const float*)d_in[2];
    const float* bih0 = (const float*)d_in[3];
    const float* bhh0 = (const float*)d_in[4];
    const float* Wih1 = (const float*)d_in[5];
    const float* Whh1 = (const float*)d_in[6];
    const float* bih1 = (const float*)d_in[7];
    const float* bhh1 = (const float*)d_in[8];
    const float* Wq   = (const float*)d_in[9];
    const float* bq   = (const float*)d_in[10];
    const float* Wk   = (const float*)d_in[11];
    const float* bk   = (const float*)d_in[12];
    const float* Wv   = (const float*)d_in[13];
    const float* bv   = (const float*)d_in[14];
    const float* R    = (const float*)d_in[15];
    const float* Wg   = (const float*)d_in[16];
    const float* bg   = (const float*)d_in[17];
    const float* W1   = (const float*)d_in[18];
    const float* b1   = (const float*)d_in[19];
    const float* W2   = (const float*)d_in[20];
    const float* b2   = (const float*)d_in[21];

    float* ws = (float*)d_ws;
    size_t off = 0;
    auto alloc_f = [&](size_t n) { float* p = ws + off; off += n; return p; };
    float* S1f  = alloc_f(524288);
    float* kh   = alloc_f(524288);
    float* vh   = alloc_f(524288);
    float* qh2  = alloc_f(524288);
    float* qhR  = alloc_f(7680);
    float* s1   = alloc_f(122880);
    float* Bm   = alloc_f(7680);
    float* kh2  = alloc_f(7680);
    float* vh2  = alloc_f(7680);
    float* Smix = alloc_f(524288);
    float* S2   = alloc_f(524288);
    float* yv   = alloc_f(2048);
    float* W1T  = alloc_f(65536);
    unsigned short* us = (unsigned short*)(ws + off);
    size_t uoff = 0;
    auto alloc_u = [&](size_t n) { unsigned short* p = us + uoff; uoff += n; return p; };
    unsigned short* H0hi[2] = { alloc_u(524288), alloc_u(524288) };
    unsigned short* H0lo[2] = { alloc_u(524288), alloc_u(524288) };
    unsigned short* H1hi[2] = { alloc_u(524288), alloc_u(524288) };
    unsigned short* H1lo[2] = { alloc_u(524288), alloc_u(524288) };
    unsigned short* FB0hi = alloc_u(245760);
    unsigned short* FB0lo = alloc_u(245760);
    unsigned short* FB1hi = alloc_u(393216);
    unsigned short* FB1lo = alloc_u(393216);
    unsigned short* FXhi  = alloc_u(16777216);
    unsigned* barp = (unsigned*)alloc_u(256);

    pack_w<<<960, 256, 0, stream>>>(Whh0, Wih0, 64, 320, FB0hi, FB0lo, 245760);
    pack_w<<<1536, 256, 0, stream>>>(Whh1, Wih1, 256, 512, FB1hi, FB1lo, 393216);
    pack_x<<<65536, 256, 0, stream>>>(x, FXhi);
    (void)hipMemsetAsync(H0hi[0], 0, 1048576, stream);
    (void)hipMemsetAsync(H0lo[0], 0, 1048576, stream);
    (void)hipMemsetAsync(H1hi[1], 0, 1048576, stream);
    (void)hipMemsetAsync(H1lo[1], 0, 1048576, stream);
    (void)hipMemsetAsync(Bm, 0, 30720, stream);
    (void)hipMemsetAsync(barp, 0, 512, stream);

    gru_scan<<<256, 512, 0, stream>>>(
        H0hi[0], H0lo[0], H0hi[1], H0lo[1],
        H1hi[0], H1lo[0], H1hi[1], H1lo[1],
        FXhi, FB0hi, FB0lo, FB1hi, FB1lo,
        bih0, bhh0, bih1, bhh1, S1f, barp);

    proj_gemm<<<192, 256, 0, stream>>>(S1f, Wk, bk, Wv, bv, Wq, bq, kh, vh, qh2);
    projR_kernel<<<30, 256, 0, stream>>>(R, Wq, bq, qhR);
    scores1_kernel<<<480, 256, 0, stream>>>(qhR, kh, s1);
    softmax1_kernel<<<60, 256, 0, stream>>>(s1);
    o1_kernel<<<960, 128, 0, stream>>>(s1, vh, Bm);
    proj3_kernel<<<60, 256, 0, stream>>>(Bm, 30, Wk, bk, Wv, bv, kh2, vh2);
    attn2_kernel<<<2048, 256, 0, stream>>>(qh2, kh2, vh2, S1f, Wg, bg, Smix);
    w1t_kernel<<<256, 256, 0, stream>>>(W1, W1T);
    mlp_kernel<<<2048, 256, 0, stream>>>(Smix, W1T, b1, S2);
    y_kernel<<<2048, 256, 0, stream>>>(S2, W2, b2, yv);
    norm_kernel<<<1, 1024, 0, stream>>>(yv, (float*)d_out);
}

// Round 3
// 5610.509 us; speedup vs baseline: 1.0549x; 1.0549x over previous
//
#include <hip/hip_runtime.h>
#include <hip/hip_bf16.h>

// CrossGRU round 8: persistent scan, fence diet + all-weights-in-LDS + deep A-prefetch.
// r7 (44us/step) died on the agent RELEASE fence: every block ran buffer_wbl2 (L2 dirty
// writeback) -> 32 serialized full-L2 writebacks per XCD per step, plus cold refetch
// with a 1-deep prefetch. r8: H stores are write-through (RELAXED SYSTEM atomic stores,
// sc0|sc1 -> no dirty lines to write back), barrier is {syncthreads; relaxed agent
// arrive+spin; syncthreads; ACQUIRE-agent fence (buffer_inv only)}. All weights hi+lo
// (both layers) staged in 156KB LDS once -> per-step global stream is A only, immune to
// the per-step invalidate. A-prefetch deepened to 2 kc (ring-of-3, full unroll).

#define HH  256
#define TT  128
#define INP 64
#define KH  8   // h-part kc count (256/32)

typedef float f32x4 __attribute__((ext_vector_type(4)));
typedef short bf16x8 __attribute__((ext_vector_type(8)));

#define MFMA(A,B,C) __builtin_amdgcn_mfma_f32_16x16x32_bf16((A),(B),(C),0,0,0)

__device__ __forceinline__ float bf2f(unsigned short s) {
    unsigned u = ((unsigned)s) << 16;
    float f; __builtin_memcpy(&f, &u, 4); return f;
}
__device__ __forceinline__ unsigned short f2bf(float f) {
    unsigned u; __builtin_memcpy(&u, &f, 4);
    unsigned r = (u + 0x7FFFu + ((u >> 16) & 1u)) >> 16;
    return (unsigned short)r;
}
// write-through store (sc0|sc1): completes at device coherence point, no dirty L2 line.
__device__ __forceinline__ void st_sys_u16(unsigned short* p, unsigned short v) {
    __hip_atomic_store(p, v, __ATOMIC_RELAXED, __HIP_MEMORY_SCOPE_SYSTEM);
}

// fragment-major index for element (row r, col k), K cols:
// idx = (r>>4)*(K*16) + (k>>5)*512 + ((k>>3)&3)*128 + (r&15)*8 + (k&7)

__global__ void pack_w(const float* __restrict__ Whh, const float* __restrict__ Wih,
                       int Kin, int Kw, unsigned short* __restrict__ FBhi,
                       unsigned short* __restrict__ FBlo, int total)
{
    int idx = blockIdx.x * 256 + threadIdx.x;
    if (idx >= total) return;
    int n = idx / Kw, k = idx - n * Kw;
    float v = (k < 256) ? Whh[n * 256 + k] : Wih[n * Kin + (k - 256)];
    int dst = (n >> 4) * (Kw * 16) + (k >> 5) * 512 + ((k >> 3) & 3) * 128 + (n & 15) * 8 + (k & 7);
    unsigned short h = f2bf(v);
    FBhi[dst] = h;
    FBlo[dst] = f2bf(v - bf2f(h));
}

__global__ void pack_x(const float* __restrict__ x, unsigned short* __restrict__ FXhi)
{
    int idx = blockIdx.x * 256 + threadIdx.x;  // 2048*128*64
    int k = idx & 63;
    int t = (idx >> 6) & 127;
    int m = idx >> 13;
    int dst = t * 131072 + (m >> 4) * 1024 + (k >> 5) * 512 + ((k >> 3) & 3) * 128 + (m & 15) * 8 + (k & 7);
    FXhi[dst] = f2bf(x[idx]);
}

// ---------------- B staging: global (frag-major, per-ntb slice) -> LDS ----------------
// LDS layout (shorts): Bhi[3][NKC*512] then Blo[3][NKC*512]
template<int NKC, int STRIDE>
__device__ __forceinline__ void stage_Bs(const unsigned short* __restrict__ Bhi,
                                         const unsigned short* __restrict__ Blo,
                                         short* __restrict__ sB, int ntb, int tid)
{
    const int Kw16 = NKC * 512;
#pragma unroll 1
    for (int t = tid; t < 3 * NKC * 64; t += STRIDE) {
        const int g = t / (NKC * 64);
        const int r = t - g * (NKC * 64);
        *(bf16x8*)(sB + g * Kw16 + r * 8) =
            *(const bf16x8*)(Bhi + (g * 16 + ntb) * Kw16 + r * 8);
        *(bf16x8*)(sB + 3 * Kw16 + g * Kw16 + r * 8) =
            *(const bf16x8*)(Blo + (g * 16 + ntb) * Kw16 + r * 8);
    }
}

// ---------------- GRU step core ----------------
// wave = 32 rows (2 m-tiles) x 16 ch (1 n-tile per gate), 3-term hi/lo MFMA.
// All B (hi+lo, all kc) from LDS. A prefetched 2 kc ahead (ring of 3, full unroll).
template<int NKC, bool LAY>
__device__ __forceinline__ void gru_core(
    const unsigned short* Ah_h, const unsigned short* Al_h,
    const unsigned short* Ah_x, const unsigned short* Al_x,
    const short* __restrict__ sB, int mt0, int lane,
    f32x4 (&ar)[2], f32x4 (&az)[2], f32x4 (&anh)[2], f32x4 (&anx)[2])
{
    const int Kw16 = NKC * 512;            // Kw*16
    const int xs = LAY ? 4096 : 1024;      // x-source per-m-tile stride
    const int lo8 = lane * 8;
    const short* sH = sB + lo8;
    const short* sL = sB + 3 * Kw16 + lo8;

    bf16x8 A[3][2][2];                     // ring; indices const after full unroll
    bf16x8 cB[3][2], nB[3][2];

    auto ldA = [&](int kc, bf16x8 (&Ax)[2][2]) {
        if (kc < KH) {
#pragma unroll
            for (int mt = 0; mt < 2; ++mt) {
                Ax[mt][0] = *(const bf16x8*)(Ah_h + (mt0 + mt) * 4096 + kc * 512 + lo8);
                Ax[mt][1] = *(const bf16x8*)(Al_h + (mt0 + mt) * 4096 + kc * 512 + lo8);
            }
        } else {
#pragma unroll
            for (int mt = 0; mt < 2; ++mt) {
                Ax[mt][0] = *(const bf16x8*)(Ah_x + (mt0 + mt) * xs + (kc - KH) * 512 + lo8);
                if (LAY)
                    Ax[mt][1] = *(const bf16x8*)(Al_x + (mt0 + mt) * xs + (kc - KH) * 512 + lo8);
            }
        }
    };
    auto ldB = [&](int kc, bf16x8 (&B)[3][2]) {
#pragma unroll
        for (int g = 0; g < 3; ++g) {
            B[g][0] = *(const bf16x8*)(sH + g * Kw16 + kc * 512);
            B[g][1] = *(const bf16x8*)(sL + g * Kw16 + kc * 512);
        }
    };

    ldA(0, A[0]);
    if (NKC > 1) ldA(1, A[1]);
    ldB(0, cB);
#pragma unroll
    for (int kc = 0; kc < NKC; ++kc) {
        if (kc + 2 < NKC) ldA(kc + 2, A[(kc + 2) % 3]);
        if (kc + 1 < NKC) ldB(kc + 1, nB);
        const bool hp = (kc < KH);
        const bool a3 = LAY || hp;     // 3rd (a_lo) term availability
        bf16x8 (&cA)[2][2] = A[kc % 3];
#pragma unroll
        for (int mt = 0; mt < 2; ++mt) {
            ar[mt] = MFMA(cA[mt][0], cB[0][0], ar[mt]);
            ar[mt] = MFMA(cA[mt][0], cB[0][1], ar[mt]);
            if (a3) ar[mt] = MFMA(cA[mt][1], cB[0][0], ar[mt]);
            az[mt] = MFMA(cA[mt][0], cB[1][0], az[mt]);
            az[mt] = MFMA(cA[mt][0], cB[1][1], az[mt]);
            if (a3) az[mt] = MFMA(cA[mt][1], cB[1][0], az[mt]);
            if (hp) {
                anh[mt] = MFMA(cA[mt][0], cB[2][0], anh[mt]);
                anh[mt] = MFMA(cA[mt][0], cB[2][1], anh[mt]);
                if (a3) anh[mt] = MFMA(cA[mt][1], cB[2][0], anh[mt]);
            } else {
                anx[mt] = MFMA(cA[mt][0], cB[2][0], anx[mt]);
                anx[mt] = MFMA(cA[mt][0], cB[2][1], anx[mt]);
                if (a3) anx[mt] = MFMA(cA[mt][1], cB[2][0], anx[mt]);
            }
        }
#pragma unroll
        for (int g = 0; g < 3; ++g) { cB[g][0] = nB[g][0]; cB[g][1] = nB[g][1]; }
    }
}

// Device-wide barrier, no release fence (H stores are write-through sc0|sc1):
// syncthreads drains vmcnt (stores at IC); relaxed agent arrive+spin; acquire-agent
// fence = invalidate-only (no dirty-L2 writeback scan) so next step's reads are fresh.
__device__ __forceinline__ void grid_bar(unsigned* cnt, unsigned need)
{
    __syncthreads();
    if (threadIdx.x == 0) {
        __hip_atomic_fetch_add(cnt, 1u, __ATOMIC_RELAXED, __HIP_MEMORY_SCOPE_AGENT);
        while (__hip_atomic_load(cnt, __ATOMIC_RELAXED, __HIP_MEMORY_SCOPE_AGENT) < need)
            __builtin_amdgcn_s_sleep(8);
    }
    __syncthreads();
    __builtin_amdgcn_fence(__ATOMIC_ACQUIRE, "agent");
    asm volatile("" ::: "memory");
}

// Persistent scan: 256 blocks x 512 threads. Block b: mb=b>>4 (128 rows), cb=b&15 (16 ch).
// Waves 0-3: layer0 step i; waves 4-7: layer1 step i-1. 156KB LDS forces 1 block/CU,
// grid==CU count -> all blocks co-resident, plain launch is barrier-safe.
// H pointers NOT __restrict__ (other blocks write them between barriers).
__global__ __launch_bounds__(512, 2) void gru_scan(
    unsigned short* H0hiA, unsigned short* H0loA,
    unsigned short* H0hiB, unsigned short* H0loB,
    unsigned short* H1hiA, unsigned short* H1loA,
    unsigned short* H1hiB, unsigned short* H1loB,
    const unsigned short* __restrict__ FXhi,
    const unsigned short* __restrict__ FB0hi, const unsigned short* __restrict__ FB0lo,
    const unsigned short* __restrict__ FB1hi, const unsigned short* __restrict__ FB1lo,
    const float* __restrict__ bih0, const float* __restrict__ bhh0,
    const float* __restrict__ bih1, const float* __restrict__ bhh1,
    float* __restrict__ S1f, unsigned* bar)
{
    const int bid = blockIdx.x;       // 256
    const int mb = bid >> 4, cb = bid & 15;
    const int tid = threadIdx.x;
    const int w = tid >> 6, lane = tid & 63;
    const int lay = w >> 2, wl = w & 3;
    const int l15 = lane & 15, q = lane >> 4;
    const int mt0 = mb * 8 + wl * 2;  // first 16-row tile (of 128)
    const int ntb = cb;               // 16-ch tile within gate

    // sB1: (hi+lo)[3][16*512] = 49152 shorts (96KB); sB0: (hi+lo)[3][10*512] = 30720 (60KB)
    __shared__ __align__(16) short sB[79872];
    short* sB1 = sB;
    short* sB0 = sB + 49152;
    stage_Bs<16, 512>(FB1hi, FB1lo, sB1, cb, tid);
    stage_Bs<10, 512>(FB0hi, FB0lo, sB0, cb, tid);
    __syncthreads();

    // per-thread epilogue constants (hoisted out of the scan loop)
    const float* bih = lay ? bih1 : bih0;
    const float* bhh = lay ? bhh1 : bhh0;
    const int c = (ntb << 4) + l15;   // channel 0..255
    const float brb = bih[c] + bhh[c];
    const float bzb = bih[256 + c] + bhh[256 + c];
    const float bni = bih[512 + c];
    const float bnh = bhh[512 + c];
    const int cfr = (c >> 5) * 512 + ((c >> 3) & 3) * 128 + (c & 7);

    unsigned need = 256;
    for (int i = 0; i <= TT; ++i) {
        const int p = i & 1;
        const unsigned short* H0r_hi = p ? H0hiB : H0hiA;
        const unsigned short* H0r_lo = p ? H0loB : H0loA;
        unsigned short*       H0w_hi = p ? H0hiA : H0hiB;
        unsigned short*       H0w_lo = p ? H0loA : H0loB;
        const unsigned short* H1r_hi = p ? H1hiB : H1hiA;
        const unsigned short* H1r_lo = p ? H1loB : H1loA;
        unsigned short*       H1w_hi = p ? H1hiA : H1hiB;
        unsigned short*       H1w_lo = p ? H1loA : H1loB;

        const bool active = lay ? (i >= 1) : (i < TT);
        if (active) {
            f32x4 ar[2], az[2], anh[2], anx[2];
#pragma unroll
            for (int j = 0; j < 2; ++j) {
                ar[j] = (f32x4){0.f,0.f,0.f,0.f}; az[j] = (f32x4){0.f,0.f,0.f,0.f};
                anh[j] = (f32x4){0.f,0.f,0.f,0.f}; anx[j] = (f32x4){0.f,0.f,0.f,0.f};
            }
            if (lay) {
                gru_core<16, true>(H1r_hi, H1r_lo, H0r_hi, H0r_lo, sB1,
                                   mt0, lane, ar, az, anh, anx);
            } else {
                gru_core<10, false>(H0r_hi, H0r_lo, FXhi + i * 131072,
                                    (const unsigned short*)0, sB0,
                                    mt0, lane, ar, az, anh, anx);
            }

            const unsigned short* Ahi_h = lay ? H1r_hi : H0r_hi;
            const unsigned short* Alo_h = lay ? H1r_lo : H0r_lo;
            unsigned short* Whi = lay ? H1w_hi : H0w_hi;
            unsigned short* Wlo = lay ? H1w_lo : H0w_lo;

#pragma unroll
            for (int mt = 0; mt < 2; ++mt) {
                const int mtg = mt0 + mt;
                const int fbase = mtg * 4096 + cfr;
#pragma unroll
                for (int rg = 0; rg < 4; ++rg) {
                    const int mi = q * 4 + rg;
                    const int fidx = fbase + mi * 8;
                    const float ho = bf2f(Ahi_h[fidx]) + bf2f(Alo_h[fidx]);
                    const float rr = 1.f / (1.f + expf(-(ar[mt][rg] + brb)));
                    const float zz = 1.f / (1.f + expf(-(az[mt][rg] + bzb)));
                    const float nn = tanhf(anx[mt][rg] + bni + rr * (anh[mt][rg] + bnh));
                    const float hn = (1.f - zz) * nn + zz * ho;
                    const unsigned short hb = f2bf(hn);
                    st_sys_u16(&Whi[fidx], hb);
                    st_sys_u16(&Wlo[fidx], f2bf(hn - bf2f(hb)));
                    if (lay && i == TT) S1f[(mtg * 16 + mi) * 256 + c] = hn;
                }
            }
        }
        if (i < TT) { grid_bar(bar, need); need += 256; }
    }
}

// ---------------- epilogue ----------------

__global__ __launch_bounds__(256) void proj_gemm(const float* __restrict__ S,
    const float* __restrict__ Wk, const float* __restrict__ bk,
    const float* __restrict__ Wv, const float* __restrict__ bv,
    const float* __restrict__ Wq, const float* __restrict__ bq,
    float* __restrict__ ok, float* __restrict__ ov, float* __restrict__ oq)
{
    __shared__ float sT[256][65];
    const int bid = blockIdx.x;            // 192 = 3p * 2h * 32lt
    const int p = bid >> 6;
    const int h = (bid >> 5) & 1;
    const int l0 = (bid & 31) * 64;
    const int tid = threadIdx.x;
    const float* W = (p == 0) ? Wk : ((p == 1) ? Wv : Wq);
    const float* b = (p == 0) ? bk : ((p == 1) ? bv : bq);
    float* o = (p == 0) ? ok : ((p == 1) ? ov : oq);

    for (int e = tid; e < 64 * 256; e += 256) {
        int k = e & 255, l = e >> 8;
        sT[k][l] = S[(l0 + l) * 256 + k];
    }
    __syncthreads();

    const int dg = tid & 15, lg = tid >> 4;
    const int d0 = dg * 8;
    const float* Wp = W + h * 32768 + d0;
    float acc[4][8];
#pragma unroll
    for (int i = 0; i < 4; ++i)
#pragma unroll
        for (int j = 0; j < 8; ++j) acc[i][j] = 0.f;

    for (int k = 0; k < 256; ++k) {
        f32x4 sv = *(const f32x4*)&sT[k][lg * 4];
        f32x4 w0 = *(const f32x4*)(Wp + k * 128);
        f32x4 w1 = *(const f32x4*)(Wp + k * 128 + 4);
#pragma unroll
        for (int i = 0; i < 4; ++i) {
#pragma unroll
            for (int j = 0; j < 4; ++j) {
                acc[i][j]     += sv[i] * w0[j];
                acc[i][4 + j] += sv[i] * w1[j];
            }
        }
    }
#pragma unroll
    for (int i = 0; i < 4; ++i) {
        float* op = o + (h * 2048 + l0 + lg * 4 + i) * 128 + d0;
#pragma unroll
        for (int j = 0; j < 8; ++j) op[j] = acc[i][j] + b[h * 128 + d0 + j];
    }
}

__global__ void proj3_kernel(const float* __restrict__ A, int M,
    const float* __restrict__ Wk, const float* __restrict__ bk,
    const float* __restrict__ Wv, const float* __restrict__ bv,
    float* __restrict__ ok, float* __restrict__ ov)
{
    int idx = blockIdx.x * 256 + threadIdx.x;
    if (idx >= 2 * 2 * M * 128) return;
    int d = idx & 127;
    int rest = idx >> 7;
    int l = rest % M;
    int ph = rest / M;
    int h = ph & 1, p = ph >> 1;
    const float* W = (p == 0) ? Wk : Wv;
    const float* b = (p == 0) ? bk : bv;
    float* o = (p == 0) ? ok : ov;
    float accv = b[h * 128 + d];
    const float* a = A + l * 256;
    const float* wp = W + h * (256 * 128) + d;
    for (int j = 0; j < 256; ++j) accv += a[j] * wp[j * 128];
    o[(h * M + l) * 128 + d] = accv;
}

__global__ void projR_kernel(const float* __restrict__ R,
    const float* __restrict__ Wq, const float* __restrict__ bq,
    float* __restrict__ oq)
{
    int idx = blockIdx.x * 256 + threadIdx.x;
    if (idx >= 2 * 30 * 128) return;
    int d = idx & 127;
    int rest = idx >> 7;
    int l = rest % 30;
    int h = rest / 30;
    float a = bq[h * 128 + d];
    const float* r = R + l * 256;
    const float* wp = Wq + h * 32768 + d;
    for (int j = 0; j < 256; ++j) a += r[j] * wp[j * 128];
    oq[(h * 30 + l) * 128 + d] = a;
}

__global__ void scores1_kernel(const float* __restrict__ qhR, const float* __restrict__ kh,
                               float* __restrict__ s1)
{
    int idx = blockIdx.x * 256 + threadIdx.x;
    if (idx >= 2 * 30 * 2048) return;
    int k = idx & 2047;
    int rest = idx >> 11;
    int i = rest % 30;
    int h = rest / 30;
    const f32x4* qp = (const f32x4*)(qhR + (h * 30 + i) * 128);
    const f32x4* kp = (const f32x4*)(kh + (h * 2048 + k) * 128);
    float acc = 0.f;
    for (int dd = 0; dd < 32; ++dd) {
        f32x4 a = qp[dd], b = kp[dd];
        acc += a[0] * b[0] + a[1] * b[1] + a[2] * b[2] + a[3] * b[3];
    }
    s1[idx] = acc * 0.08838834764831845f;
}

__global__ void softmax1_kernel(float* __restrict__ s1)
{
    __shared__ float red[256];
    float* p = s1 + blockIdx.x * 2048;
    int tid = threadIdx.x;
    float mx = -1e30f;
    for (int k = tid; k < 2048; k += 256) mx = fmaxf(mx, p[k]);
    red[tid] = mx; __syncthreads();
    for (int s = 128; s > 0; s >>= 1) { if (tid < s) red[tid] = fmaxf(red[tid], red[tid + s]); __syncthreads(); }
    mx = red[0]; __syncthreads();
    float sum = 0.f;
    for (int k = tid; k < 2048; k += 256) { float e = expf(p[k] - mx); p[k] = e; sum += e; }
    red[tid] = sum; __syncthreads();
    for (int s = 128; s > 0; s >>= 1) { if (tid < s) red[tid] += red[tid + s]; __syncthreads(); }
    float inv = 1.f / red[0];
    for (int k = tid; k < 2048; k += 256) p[k] *= inv;
}

// split-K o1: 16 k-slices per output row, fp32 atomicAdd into zeroed Bm.
__global__ void o1_kernel(const float* __restrict__ p1, const float* __restrict__ vh,
                          float* __restrict__ Bm)
{
    int bid = blockIdx.x;            // 60 rows * 16 k-slices
    int row = bid >> 4;              // h*30+i
    int ks = bid & 15;
    int h = row / 30;
    int i = row % 30;
    int d = threadIdx.x;             // 128
    const float* pp = p1 + row * 2048 + ks * 128;
    const float* vp = vh + (h * 2048 + ks * 128) * 128 + d;
    float acc = 0.f;
    for (int k = 0; k < 128; ++k) acc += pp[k] * vp[k * 128];
    atomicAdd(&Bm[i * 256 + h * 128 + d], acc);
}

__global__ __launch_bounds__(256) void attn2_kernel(
    const float* __restrict__ qh2, const float* __restrict__ kh2, const float* __restrict__ vh2,
    const float* __restrict__ S, const float* __restrict__ Wg,
    const float* __restrict__ bg, float* __restrict__ Smix)
{
    __shared__ float ks[2 * 30 * 129];
    __shared__ float qred[256];
    __shared__ float ps[64];
    int l = blockIdx.x;
    int tid = threadIdx.x;
    for (int idx = tid; idx < 2 * 30 * 128; idx += 256) {
        int hh = idx / 3840; int rem = idx - hh * 3840;
        int j = rem >> 7; int d = rem & 127;
        ks[(hh * 30 + j) * 129 + d] = kh2[idx];
    }
    int h = tid >> 7, d = tid & 127;
    qred[tid] = qh2[(h * 2048 + l) * 128 + d];
    __syncthreads();
    int w = tid >> 6, lane = tid & 63;
    if (w < 2 && lane < 32) {
        float sc = -1e30f;
        if (lane < 30) {
            const float* qp = qred + w * 128;
            float a = 0.f;
            for (int dd = 0; dd < 128; ++dd) a += qp[dd] * ks[(w * 30 + lane) * 129 + dd];
            sc = a * 0.08838834764831845f;
        }
        float mx = sc;
        for (int m = 16; m > 0; m >>= 1) mx = fmaxf(mx, __shfl_xor(mx, m, 32));
        float e = (lane < 30) ? expf(sc - mx) : 0.f;
        float sm = e;
        for (int m = 16; m > 0; m >>= 1) sm += __shfl_xor(sm, m, 32);
        ps[w * 32 + lane] = e / sm;
    }
    __syncthreads();
    float o = 0.f;
    const float* vp = vh2 + h * 3840 + d;
    for (int j = 0; j < 30; ++j) o += ps[h * 32 + j] * vp[j * 128];
    float sl = S[l * 256 + tid];
    qred[tid] = sl * Wg[tid];
    __syncthreads();
    for (int s = 128; s > 0; s >>= 1) { if (tid < s) qred[tid] += qred[tid + s]; __syncthreads(); }
    float alpha = 1.f / (1.f + expf(-(qred[0] + bg[0])));
    Smix[l * 256 + tid] = alpha * o + (1.f - alpha) * sl;
}

__global__ void w1t_kernel(const float* __restrict__ W1, float* __restrict__ W1T)
{
    int idx = blockIdx.x * 256 + threadIdx.x;  // 65536
    int j = idx & 255, c = idx >> 8;
    W1T[j * 256 + c] = W1[c * 256 + j];
}

__global__ void mlp_kernel(const float* __restrict__ Smix, const float* __restrict__ W1T,
                           const float* __restrict__ b1, float* __restrict__ S2)
{
    int idx = blockIdx.x * 256 + threadIdx.x;  // l*256+c
    int c = idx & 255; int l = idx >> 8;
    const float* a = Smix + l * 256;
    float acc = b1[c];
    for (int j = 0; j < 256; ++j) acc += a[j] * W1T[j * 256 + c];
    float v = fmaxf(acc, 0.f);
    S2[idx] = v + a[c];
}

__global__ void y_kernel(const float* __restrict__ S2, const float* __restrict__ W2,
                         const float* __restrict__ b2, float* __restrict__ y)
{
    __shared__ float red[256];
    int l = blockIdx.x; int tid = threadIdx.x;
    red[tid] = S2[l * 256 + tid] * W2[tid];
    __syncthreads();
    for (int s = 128; s > 0; s >>= 1) { if (tid < s) red[tid] += red[tid + s]; __syncthreads(); }
    if (tid == 0) y[l] = red[0] + b2[0];
}

__global__ void norm_kernel(const float* __restrict__ y, float* __restrict__ out)
{
    __shared__ float r1[1024], r2[1024];
    int tid = threadIdx.x;
    float s1v = 0.f, s2v = 0.f;
    for (int idx = tid; idx < 2048; idx += 1024) { float v = y[idx]; s1v += v; s2v += v * v; }
    r1[tid] = s1v; r2[tid] = s2v; __syncthreads();
    for (int s = 512; s > 0; s >>= 1) {
        if (tid < s) { r1[tid] += r1[tid + s]; r2[tid] += r2[tid + s]; }
        __syncthreads();
    }
    float mean = r1[0] / 2048.f;
    float var = fmaxf((r2[0] - 2048.f * mean * mean) / 2047.f, 0.f);
    float inv = 1.f / (sqrtf(var) + 1e-8f);
    for (int idx = tid; idx < 2048; idx += 1024)
        out[idx] = (y[idx] - mean) * inv;
}

extern "C" void kernel_launch(void* const* d_in, const int* in_sizes, int n_in,
                              void* d_out, int out_size, void* d_ws, size_t ws_size,
                              hipStream_t stream)
{
    const float* x    = (const float*)d_in[0];
    const float* Wih0 = (const float*)d_in[1];
    const float* Whh0 = (const float*)d_in[2];
    const float* bih0 = (const float*)d_in[3];
    const float* bhh0 = (const float*)d_in[4];
    const float* Wih1 = (const float*)d_in[5];
    const float* Whh1 = (const float*)d_in[6];
    const float* bih1 = (const float*)d_in[7];
    const float* bhh1 = (const float*)d_in[8];
    const float* Wq   = (const float*)d_in[9];
    const float* bq   = (const float*)d_in[10];
    const float* Wk   = (const float*)d_in[11];
    const float* bk   = (const float*)d_in[12];
    const float* Wv   = (const float*)d_in[13];
    const float* bv   = (const float*)d_in[14];
    const float* R    = (const float*)d_in[15];
    const float* Wg   = (const float*)d_in[16];
    const float* bg   = (const float*)d_in[17];
    const float* W1   = (const float*)d_in[18];
    const float* b1   = (const float*)d_in[19];
    const float* W2   = (const float*)d_in[20];
    const float* b2   = (const float*)d_in[21];

    float* ws = (float*)d_ws;
    size_t off = 0;
    auto alloc_f = [&](size_t n) { float* p = ws + off; off += n; return p; };
    float* S1f  = alloc_f(524288);
    float* kh   = alloc_f(524288);
    float* vh   = alloc_f(524288);
    float* qh2  = alloc_f(524288);
    float* qhR  = alloc_f(7680);
    float* s1   = alloc_f(122880);
    float* Bm   = alloc_f(7680);
    float* kh2  = alloc_f(7680);
    float* vh2  = alloc_f(7680);
    float* Smix = alloc_f(524288);
    float* S2   = alloc_f(524288);
    float* yv   = alloc_f(2048);
    float* W1T  = alloc_f(65536);
    unsigned short* us = (unsigned short*)(ws + off);
    size_t uoff = 0;
    auto alloc_u = [&](size_t n) { unsigned short* p = us + uoff; uoff += n; return p; };
    unsigned short* H0hi[2] = { alloc_u(524288), alloc_u(524288) };
    unsigned short* H0lo[2] = { alloc_u(524288), alloc_u(524288) };
    unsigned short* H1hi[2] = { alloc_u(524288), alloc_u(524288) };
    unsigned short* H1lo[2] = { alloc_u(524288), alloc_u(524288) };
    unsigned short* FB0hi = alloc_u(245760);
    unsigned short* FB0lo = alloc_u(245760);
    unsigned short* FB1hi = alloc_u(393216);
    unsigned short* FB1lo = alloc_u(393216);
    unsigned short* FXhi  = alloc_u(16777216);
    unsigned* barp = (unsigned*)alloc_u(256);

    pack_w<<<960, 256, 0, stream>>>(Whh0, Wih0, 64, 320, FB0hi, FB0lo, 245760);
    pack_w<<<1536, 256, 0, stream>>>(Whh1, Wih1, 256, 512, FB1hi, FB1lo, 393216);
    pack_x<<<65536, 256, 0, stream>>>(x, FXhi);
    (void)hipMemsetAsync(H0hi[0], 0, 1048576, stream);
    (void)hipMemsetAsync(H0lo[0], 0, 1048576, stream);
    (void)hipMemsetAsync(H1hi[1], 0, 1048576, stream);
    (void)hipMemsetAsync(H1lo[1], 0, 1048576, stream);
    (void)hipMemsetAsync(Bm, 0, 30720, stream);
    (void)hipMemsetAsync(barp, 0, 512, stream);

    gru_scan<<<256, 512, 0, stream>>>(
        H0hi[0], H0lo[0], H0hi[1], H0lo[1],
        H1hi[0], H1lo[0], H1hi[1], H1lo[1],
        FXhi, FB0hi, FB0lo, FB1hi, FB1lo,
        bih0, bhh0, bih1, bhh1, S1f, barp);

    proj_gemm<<<192, 256, 0, stream>>>(S1f, Wk, bk, Wv, bv, Wq, bq, kh, vh, qh2);
    projR_kernel<<<30, 256, 0, stream>>>(R, Wq, bq, qhR);
    scores1_kernel<<<480, 256, 0, stream>>>(qhR, kh, s1);
    softmax1_kernel<<<60, 256, 0, stream>>>(s1);
    o1_kernel<<<960, 128, 0, stream>>>(s1, vh, Bm);
    proj3_kernel<<<60, 256, 0, stream>>>(Bm, 30, Wk, bk, Wv, bv, kh2, vh2);
    attn2_kernel<<<2048, 256, 0, stream>>>(qh2, kh2, vh2, S1f, Wg, bg, Smix);
    w1t_kernel<<<256, 256, 0, stream>>>(W1, W1T);
    mlp_kernel<<<2048, 256, 0, stream>>>(Smix, W1T, b1, S2);
    y_kernel<<<2048, 256, 0, stream>>>(S2, W2, b2, yv);
    norm_kernel<<<1, 1024, 0, stream>>>(yv, (float*)d_out);
}

// Round 4
// 2056.968 us; speedup vs baseline: 2.8773x; 2.7276x over previous
//
#include <hip/hip_runtime.h>
#include <hip/hip_bf16.h>

// CrossGRU round 9: XCD-local persistent scan — zero coherence ops in the loop.
// r7/r8 both sat at ~42us/step regardless of fence flavor: the shared cost was
// per-step L2 coherence (wave-count buffer_inv / wbl2 serialized at TCC + 18.7MB/step
// fabric refetch). r9 partitions ROWS BY XCD (rows are independent in a GRU step; only
// the K=256 reduction couples channel-blocks, kept within the XCD): XCD x's 32 blocks
// handle rows [256x,256x+256) as 2 row-halves x 16 ch-tiles. H stores are plain (L1 is
// write-through -> local L2); H loads are agent-scope relaxed u64 atomics (sc0: bypass
// stale per-CU L1, hit local L2); barrier is per-XCD (32 blocks, relaxed agent atomics,
// no fences). Placement made correct by construction: 156KB LDS forces 1 block/CU ->
// each XCD hosts exactly 32 blocks; blocks read real XCC_ID (s_getreg, m09) and claim
// a slot via per-XCD atomic counter. Weights in LDS once; FX/bias read-only cached.

#define HH  256
#define TT  128
#define INP 64
#define KH  8   // h-part kc count (256/32)

typedef float f32x4 __attribute__((ext_vector_type(4)));
typedef short bf16x8 __attribute__((ext_vector_type(8)));
typedef unsigned long long u64;

#define MFMA(A,B,C) __builtin_amdgcn_mfma_f32_16x16x32_bf16((A),(B),(C),0,0,0)

__device__ __forceinline__ float bf2f(unsigned short s) {
    unsigned u = ((unsigned)s) << 16;
    float f; __builtin_memcpy(&f, &u, 4); return f;
}
__device__ __forceinline__ unsigned short f2bf(float f) {
    unsigned u; __builtin_memcpy(&u, &f, 4);
    unsigned r = (u + 0x7FFFu + ((u >> 16) & 1u)) >> 16;
    return (unsigned short)r;
}

// L1-bypass (sc0) 16B load as two agent-scope relaxed u64 atomic loads: reads the
// XCD-local L2 copy (fresh within the XCD), never the per-CU L1.
__device__ __forceinline__ bf16x8 ldH(const unsigned short* p) {
    union { u64 q[2]; bf16x8 v; } u;
    u.q[0] = __hip_atomic_load((u64*)p,       __ATOMIC_RELAXED, __HIP_MEMORY_SCOPE_AGENT);
    u.q[1] = __hip_atomic_load((u64*)(p + 4), __ATOMIC_RELAXED, __HIP_MEMORY_SCOPE_AGENT);
    return u.v;
}

// fragment-major index for element (row r, col k), K cols:
// idx = (r>>4)*(K*16) + (k>>5)*512 + ((k>>3)&3)*128 + (r&15)*8 + (k&7)

__global__ void pack_w(const float* __restrict__ Whh, const float* __restrict__ Wih,
                       int Kin, int Kw, unsigned short* __restrict__ FBhi,
                       unsigned short* __restrict__ FBlo, int total)
{
    int idx = blockIdx.x * 256 + threadIdx.x;
    if (idx >= total) return;
    int n = idx / Kw, k = idx - n * Kw;
    float v = (k < 256) ? Whh[n * 256 + k] : Wih[n * Kin + (k - 256)];
    int dst = (n >> 4) * (Kw * 16) + (k >> 5) * 512 + ((k >> 3) & 3) * 128 + (n & 15) * 8 + (k & 7);
    unsigned short h = f2bf(v);
    FBhi[dst] = h;
    FBlo[dst] = f2bf(v - bf2f(h));
}

__global__ void pack_x(const float* __restrict__ x, unsigned short* __restrict__ FXhi)
{
    int idx = blockIdx.x * 256 + threadIdx.x;  // 2048*128*64
    int k = idx & 63;
    int t = (idx >> 6) & 127;
    int m = idx >> 13;
    int dst = t * 131072 + (m >> 4) * 1024 + (k >> 5) * 512 + ((k >> 3) & 3) * 128 + (m & 15) * 8 + (k & 7);
    FXhi[dst] = f2bf(x[idx]);
}

// ---------------- B staging: global (frag-major, per-ntb slice) -> LDS ----------------
// LDS layout (shorts): Bhi[3][NKC*512] then Blo[3][NKC*512]
template<int NKC, int STRIDE>
__device__ __forceinline__ void stage_Bs(const unsigned short* __restrict__ Bhi,
                                         const unsigned short* __restrict__ Blo,
                                         short* __restrict__ sB, int ntb, int tid)
{
    const int Kw16 = NKC * 512;
#pragma unroll 1
    for (int t = tid; t < 3 * NKC * 64; t += STRIDE) {
        const int g = t / (NKC * 64);
        const int r = t - g * (NKC * 64);
        *(bf16x8*)(sB + g * Kw16 + r * 8) =
            *(const bf16x8*)(Bhi + (g * 16 + ntb) * Kw16 + r * 8);
        *(bf16x8*)(sB + 3 * Kw16 + g * Kw16 + r * 8) =
            *(const bf16x8*)(Blo + (g * 16 + ntb) * Kw16 + r * 8);
    }
}

// ---------------- GRU step core ----------------
// wave = 32 rows (2 m-tiles) x 16 ch (1 n-tile per gate), 3-term hi/lo MFMA.
// All B (hi+lo, all kc) from LDS. A prefetched 2 kc ahead (ring of 3, full unroll).
// H reads use ldH (sc0, L1-bypass); FX reads (LAY=false x-part) plain cached.
template<int NKC, bool LAY>
__device__ __forceinline__ void gru_core(
    const unsigned short* Ah_h, const unsigned short* Al_h,
    const unsigned short* Ah_x, const unsigned short* Al_x,
    const short* __restrict__ sB, int mt0, int lane,
    f32x4 (&ar)[2], f32x4 (&az)[2], f32x4 (&anh)[2], f32x4 (&anx)[2])
{
    const int Kw16 = NKC * 512;            // Kw*16
    const int xs = LAY ? 4096 : 1024;      // x-source per-m-tile stride
    const int lo8 = lane * 8;
    const short* sH = sB + lo8;
    const short* sL = sB + 3 * Kw16 + lo8;

    bf16x8 A[3][2][2];                     // ring; indices const after full unroll
    bf16x8 cB[3][2], nB[3][2];

    auto ldA = [&](int kc, bf16x8 (&Ax)[2][2]) {
        if (kc < KH) {
#pragma unroll
            for (int mt = 0; mt < 2; ++mt) {
                Ax[mt][0] = ldH(Ah_h + (mt0 + mt) * 4096 + kc * 512 + lo8);
                Ax[mt][1] = ldH(Al_h + (mt0 + mt) * 4096 + kc * 512 + lo8);
            }
        } else {
#pragma unroll
            for (int mt = 0; mt < 2; ++mt) {
                if (LAY) {
                    Ax[mt][0] = ldH(Ah_x + (mt0 + mt) * xs + (kc - KH) * 512 + lo8);
                    Ax[mt][1] = ldH(Al_x + (mt0 + mt) * xs + (kc - KH) * 512 + lo8);
                } else {
                    Ax[mt][0] = *(const bf16x8*)(Ah_x + (mt0 + mt) * xs + (kc - KH) * 512 + lo8);
                }
            }
        }
    };
    auto ldB = [&](int kc, bf16x8 (&B)[3][2]) {
#pragma unroll
        for (int g = 0; g < 3; ++g) {
            B[g][0] = *(const bf16x8*)(sH + g * Kw16 + kc * 512);
            B[g][1] = *(const bf16x8*)(sL + g * Kw16 + kc * 512);
        }
    };

    ldA(0, A[0]);
    if (NKC > 1) ldA(1, A[1]);
    ldB(0, cB);
#pragma unroll
    for (int kc = 0; kc < NKC; ++kc) {
        if (kc + 2 < NKC) ldA(kc + 2, A[(kc + 2) % 3]);
        if (kc + 1 < NKC) ldB(kc + 1, nB);
        const bool hp = (kc < KH);
        const bool a3 = LAY || hp;     // 3rd (a_lo) term availability
        bf16x8 (&cA)[2][2] = A[kc % 3];
#pragma unroll
        for (int mt = 0; mt < 2; ++mt) {
            ar[mt] = MFMA(cA[mt][0], cB[0][0], ar[mt]);
            ar[mt] = MFMA(cA[mt][0], cB[0][1], ar[mt]);
            if (a3) ar[mt] = MFMA(cA[mt][1], cB[0][0], ar[mt]);
            az[mt] = MFMA(cA[mt][0], cB[1][0], az[mt]);
            az[mt] = MFMA(cA[mt][0], cB[1][1], az[mt]);
            if (a3) az[mt] = MFMA(cA[mt][1], cB[1][0], az[mt]);
            if (hp) {
                anh[mt] = MFMA(cA[mt][0], cB[2][0], anh[mt]);
                anh[mt] = MFMA(cA[mt][0], cB[2][1], anh[mt]);
                if (a3) anh[mt] = MFMA(cA[mt][1], cB[2][0], anh[mt]);
            } else {
                anx[mt] = MFMA(cA[mt][0], cB[2][0], anx[mt]);
                anx[mt] = MFMA(cA[mt][0], cB[2][1], anx[mt]);
                if (a3) anx[mt] = MFMA(cA[mt][1], cB[2][0], anx[mt]);
            }
        }
#pragma unroll
        for (int g = 0; g < 3; ++g) { cB[g][0] = nB[g][0]; cB[g][1] = nB[g][1]; }
    }
}

// Per-XCD barrier: 32 blocks on one counter. No fences: stores drained by the
// pre-barrier syncthreads (write-through L1 -> local L2); readers use sc0 loads.
__device__ __forceinline__ void xcd_bar(unsigned* cnt, unsigned need)
{
    __syncthreads();
    if (threadIdx.x == 0) {
        __hip_atomic_fetch_add(cnt, 1u, __ATOMIC_RELAXED, __HIP_MEMORY_SCOPE_AGENT);
        while (__hip_atomic_load(cnt, __ATOMIC_RELAXED, __HIP_MEMORY_SCOPE_AGENT) < need)
            __builtin_amdgcn_s_sleep(1);
    }
    __syncthreads();
    asm volatile("" ::: "memory");
}

// Persistent scan: 256 blocks x 512 threads, 1 block/CU (156KB LDS) -> each XCD hosts
// exactly 32 blocks (pigeonhole). Block claims (row-half, ch-tile) within ITS OWN XCD.
// Waves 0-3: layer0 step i; waves 4-7: layer1 step i-1.
__global__ __launch_bounds__(512, 2) void gru_scan(
    unsigned short* H0hiA, unsigned short* H0loA,
    unsigned short* H0hiB, unsigned short* H0loB,
    unsigned short* H1hiA, unsigned short* H1loA,
    unsigned short* H1hiB, unsigned short* H1loB,
    const unsigned short* __restrict__ FXhi,
    const unsigned short* __restrict__ FB0hi, const unsigned short* __restrict__ FB0lo,
    const unsigned short* __restrict__ FB1hi, const unsigned short* __restrict__ FB1lo,
    const float* __restrict__ bih0, const float* __restrict__ bhh0,
    const float* __restrict__ bih1, const float* __restrict__ bhh1,
    float* __restrict__ S1f, unsigned* bar, int* xslot)
{
    const int tid = threadIdx.x;
    int xcc;
    asm volatile("s_getreg_b32 %0, hwreg(HW_REG_XCC_ID)" : "=s"(xcc));
    xcc &= 7;
    __shared__ int sSlot;
    if (tid == 0) sSlot = atomicAdd(&xslot[xcc], 1) & 31;   // device-scope claim
    __syncthreads();
    const int slot = sSlot;           // 0..31 within this XCD
    const int mb2 = slot >> 4;        // row-half (128 rows) of the XCD's 256 rows
    const int cb = slot & 15;         // 16-ch tile within gate
    const int w = tid >> 6, lane = tid & 63;
    const int lay = w >> 2, wl = w & 3;
    const int l15 = lane & 15, q = lane >> 4;
    const int mt0 = xcc * 16 + mb2 * 8 + wl * 2;  // first 16-row tile (of 128)
    const int ntb = cb;
    unsigned* cnt = bar + xcc * 32;   // per-XCD counter, 128B apart

    // sB1: (hi+lo)[3][16*512] = 49152 shorts (96KB); sB0: (hi+lo)[3][10*512] = 30720 (60KB)
    __shared__ __align__(16) short sB[79872];
    short* sB1 = sB;
    short* sB0 = sB + 49152;
    stage_Bs<16, 512>(FB1hi, FB1lo, sB1, cb, tid);
    stage_Bs<10, 512>(FB0hi, FB0lo, sB0, cb, tid);
    __syncthreads();

    // per-thread epilogue constants (hoisted out of the scan loop)
    const float* bih = lay ? bih1 : bih0;
    const float* bhh = lay ? bhh1 : bhh0;
    const int c = (ntb << 4) + l15;   // channel 0..255
    const float brb = bih[c] + bhh[c];
    const float bzb = bih[256 + c] + bhh[256 + c];
    const float bni = bih[512 + c];
    const float bnh = bhh[512 + c];
    const int cfr = (c >> 5) * 512 + ((c >> 3) & 3) * 128 + (c & 7);

    for (int i = 0; i <= TT; ++i) {
        const int p = i & 1;
        const unsigned short* H0r_hi = p ? H0hiB : H0hiA;
        const unsigned short* H0r_lo = p ? H0loB : H0loA;
        unsigned short*       H0w_hi = p ? H0hiA : H0hiB;
        unsigned short*       H0w_lo = p ? H0loA : H0loB;
        const unsigned short* H1r_hi = p ? H1hiB : H1hiA;
        const unsigned short* H1r_lo = p ? H1loB : H1loA;
        unsigned short*       H1w_hi = p ? H1hiA : H1hiB;
        unsigned short*       H1w_lo = p ? H1loA : H1loB;

        const bool active = lay ? (i >= 1) : (i < TT);
        if (active) {
            f32x4 ar[2], az[2], anh[2], anx[2];
#pragma unroll
            for (int j = 0; j < 2; ++j) {
                ar[j] = (f32x4){0.f,0.f,0.f,0.f}; az[j] = (f32x4){0.f,0.f,0.f,0.f};
                anh[j] = (f32x4){0.f,0.f,0.f,0.f}; anx[j] = (f32x4){0.f,0.f,0.f,0.f};
            }
            if (lay) {
                gru_core<16, true>(H1r_hi, H1r_lo, H0r_hi, H0r_lo, sB1,
                                   mt0, lane, ar, az, anh, anx);
            } else {
                gru_core<10, false>(H0r_hi, H0r_lo, FXhi + i * 131072,
                                    (const unsigned short*)0, sB0,
                                    mt0, lane, ar, az, anh, anx);
            }

            const unsigned short* Ahi_h = lay ? H1r_hi : H0r_hi;
            const unsigned short* Alo_h = lay ? H1r_lo : H0r_lo;
            unsigned short* Whi = lay ? H1w_hi : H0w_hi;
            unsigned short* Wlo = lay ? H1w_lo : H0w_lo;

#pragma unroll
            for (int mt = 0; mt < 2; ++mt) {
                const int mtg = mt0 + mt;
                const int fbase = mtg * 4096 + cfr;
#pragma unroll
                for (int rg = 0; rg < 4; ++rg) {
                    const int mi = q * 4 + rg;
                    const int fidx = fbase + mi * 8;
                    const float ho = bf2f(Ahi_h[fidx]) + bf2f(Alo_h[fidx]);
                    const float rr = 1.f / (1.f + expf(-(ar[mt][rg] + brb)));
                    const float zz = 1.f / (1.f + expf(-(az[mt][rg] + bzb)));
                    const float nn = tanhf(anx[mt][rg] + bni + rr * (anh[mt][rg] + bnh));
                    const float hn = (1.f - zz) * nn + zz * ho;
                    const unsigned short hb = f2bf(hn);
                    Whi[fidx] = hb;
                    Wlo[fidx] = f2bf(hn - bf2f(hb));
                    if (lay && i == TT) S1f[(mtg * 16 + mi) * 256 + c] = hn;
                }
            }
        }
        if (i < TT) xcd_bar(cnt, 32u * (unsigned)(i + 1));
    }
}

// ---------------- epilogue ----------------

__global__ __launch_bounds__(256) void proj_gemm(const float* __restrict__ S,
    const float* __restrict__ Wk, const float* __restrict__ bk,
    const float* __restrict__ Wv, const float* __restrict__ bv,
    const float* __restrict__ Wq, const float* __restrict__ bq,
    float* __restrict__ ok, float* __restrict__ ov, float* __restrict__ oq)
{
    __shared__ float sT[256][65];
    const int bid = blockIdx.x;            // 192 = 3p * 2h * 32lt
    const int p = bid >> 6;
    const int h = (bid >> 5) & 1;
    const int l0 = (bid & 31) * 64;
    const int tid = threadIdx.x;
    const float* W = (p == 0) ? Wk : ((p == 1) ? Wv : Wq);
    const float* b = (p == 0) ? bk : ((p == 1) ? bv : bq);
    float* o = (p == 0) ? ok : ((p == 1) ? ov : oq);

    for (int e = tid; e < 64 * 256; e += 256) {
        int k = e & 255, l = e >> 8;
        sT[k][l] = S[(l0 + l) * 256 + k];
    }
    __syncthreads();

    const int dg = tid & 15, lg = tid >> 4;
    const int d0 = dg * 8;
    const float* Wp = W + h * 32768 + d0;
    float acc[4][8];
#pragma unroll
    for (int i = 0; i < 4; ++i)
#pragma unroll
        for (int j = 0; j < 8; ++j) acc[i][j] = 0.f;

    for (int k = 0; k < 256; ++k) {
        f32x4 sv = *(const f32x4*)&sT[k][lg * 4];
        f32x4 w0 = *(const f32x4*)(Wp + k * 128);
        f32x4 w1 = *(const f32x4*)(Wp + k * 128 + 4);
#pragma unroll
        for (int i = 0; i < 4; ++i) {
#pragma unroll
            for (int j = 0; j < 4; ++j) {
                acc[i][j]     += sv[i] * w0[j];
                acc[i][4 + j] += sv[i] * w1[j];
            }
        }
    }
#pragma unroll
    for (int i = 0; i < 4; ++i) {
        float* op = o + (h * 2048 + l0 + lg * 4 + i) * 128 + d0;
#pragma unroll
        for (int j = 0; j < 8; ++j) op[j] = acc[i][j] + b[h * 128 + d0 + j];
    }
}

__global__ void proj3_kernel(const float* __restrict__ A, int M,
    const float* __restrict__ Wk, const float* __restrict__ bk,
    const float* __restrict__ Wv, const float* __restrict__ bv,
    float* __restrict__ ok, float* __restrict__ ov)
{
    int idx = blockIdx.x * 256 + threadIdx.x;
    if (idx >= 2 * 2 * M * 128) return;
    int d = idx & 127;
    int rest = idx >> 7;
    int l = rest % M;
    int ph = rest / M;
    int h = ph & 1, p = ph >> 1;
    const float* W = (p == 0) ? Wk : Wv;
    const float* b = (p == 0) ? bk : bv;
    float* o = (p == 0) ? ok : ov;
    float accv = b[h * 128 + d];
    const float* a = A + l * 256;
    const float* wp = W + h * (256 * 128) + d;
    for (int j = 0; j < 256; ++j) accv += a[j] * wp[j * 128];
    o[(h * M + l) * 128 + d] = accv;
}

__global__ void projR_kernel(const float* __restrict__ R,
    const float* __restrict__ Wq, const float* __restrict__ bq,
    float* __restrict__ oq)
{
    int idx = blockIdx.x * 256 + threadIdx.x;
    if (idx >= 2 * 30 * 128) return;
    int d = idx & 127;
    int rest = idx >> 7;
    int l = rest % 30;
    int h = rest / 30;
    float a = bq[h * 128 + d];
    const float* r = R + l * 256;
    const float* wp = Wq + h * 32768 + d;
    for (int j = 0; j < 256; ++j) a += r[j] * wp[j * 128];
    oq[(h * 30 + l) * 128 + d] = a;
}

__global__ void scores1_kernel(const float* __restrict__ qhR, const float* __restrict__ kh,
                               float* __restrict__ s1)
{
    int idx = blockIdx.x * 256 + threadIdx.x;
    if (idx >= 2 * 30 * 2048) return;
    int k = idx & 2047;
    int rest = idx >> 11;
    int i = rest % 30;
    int h = rest / 30;
    const f32x4* qp = (const f32x4*)(qhR + (h * 30 + i) * 128);
    const f32x4* kp = (const f32x4*)(kh + (h * 2048 + k) * 128);
    float acc = 0.f;
    for (int dd = 0; dd < 32; ++dd) {
        f32x4 a = qp[dd], b = kp[dd];
        acc += a[0] * b[0] + a[1] * b[1] + a[2] * b[2] + a[3] * b[3];
    }
    s1[idx] = acc * 0.08838834764831845f;
}

__global__ void softmax1_kernel(float* __restrict__ s1)
{
    __shared__ float red[256];
    float* p = s1 + blockIdx.x * 2048;
    int tid = threadIdx.x;
    float mx = -1e30f;
    for (int k = tid; k < 2048; k += 256) mx = fmaxf(mx, p[k]);
    red[tid] = mx; __syncthreads();
    for (int s = 128; s > 0; s >>= 1) { if (tid < s) red[tid] = fmaxf(red[tid], red[tid + s]); __syncthreads(); }
    mx = red[0]; __syncthreads();
    float sum = 0.f;
    for (int k = tid; k < 2048; k += 256) { float e = expf(p[k] - mx); p[k] = e; sum += e; }
    red[tid] = sum; __syncthreads();
    for (int s = 128; s > 0; s >>= 1) { if (tid < s) red[tid] += red[tid + s]; __syncthreads(); }
    float inv = 1.f / red[0];
    for (int k = tid; k < 2048; k += 256) p[k] *= inv;
}

// split-K o1: 16 k-slices per output row, fp32 atomicAdd into zeroed Bm.
__global__ void o1_kernel(const float* __restrict__ p1, const float* __restrict__ vh,
                          float* __restrict__ Bm)
{
    int bid = blockIdx.x;            // 60 rows * 16 k-slices
    int row = bid >> 4;              // h*30+i
    int ks = bid & 15;
    int h = row / 30;
    int i = row % 30;
    int d = threadIdx.x;             // 128
    const float* pp = p1 + row * 2048 + ks * 128;
    const float* vp = vh + (h * 2048 + ks * 128) * 128 + d;
    float acc = 0.f;
    for (int k = 0; k < 128; ++k) acc += pp[k] * vp[k * 128];
    atomicAdd(&Bm[i * 256 + h * 128 + d], acc);
}

__global__ __launch_bounds__(256) void attn2_kernel(
    const float* __restrict__ qh2, const float* __restrict__ kh2, const float* __restrict__ vh2,
    const float* __restrict__ S, const float* __restrict__ Wg,
    const float* __restrict__ bg, float* __restrict__ Smix)
{
    __shared__ float ks[2 * 30 * 129];
    __shared__ float qred[256];
    __shared__ float ps[64];
    int l = blockIdx.x;
    int tid = threadIdx.x;
    for (int idx = tid; idx < 2 * 30 * 128; idx += 256) {
        int hh = idx / 3840; int rem = idx - hh * 3840;
        int j = rem >> 7; int d = rem & 127;
        ks[(hh * 30 + j) * 129 + d] = kh2[idx];
    }
    int h = tid >> 7, d = tid & 127;
    qred[tid] = qh2[(h * 2048 + l) * 128 + d];
    __syncthreads();
    int w = tid >> 6, lane = tid & 63;
    if (w < 2 && lane < 32) {
        float sc = -1e30f;
        if (lane < 30) {
            const float* qp = qred + w * 128;
            float a = 0.f;
            for (int dd = 0; dd < 128; ++dd) a += qp[dd] * ks[(w * 30 + lane) * 129 + dd];
            sc = a * 0.08838834764831845f;
        }
        float mx = sc;
        for (int m = 16; m > 0; m >>= 1) mx = fmaxf(mx, __shfl_xor(mx, m, 32));
        float e = (lane < 30) ? expf(sc - mx) : 0.f;
        float sm = e;
        for (int m = 16; m > 0; m >>= 1) sm += __shfl_xor(sm, m, 32);
        ps[w * 32 + lane] = e / sm;
    }
    __syncthreads();
    float o = 0.f;
    const float* vp = vh2 + h * 3840 + d;
    for (int j = 0; j < 30; ++j) o += ps[h * 32 + j] * vp[j * 128];
    float sl = S[l * 256 + tid];
    qred[tid] = sl * Wg[tid];
    __syncthreads();
    for (int s = 128; s > 0; s >>= 1) { if (tid < s) qred[tid] += qred[tid + s]; __syncthreads(); }
    float alpha = 1.f / (1.f + expf(-(qred[0] + bg[0])));
    Smix[l * 256 + tid] = alpha * o + (1.f - alpha) * sl;
}

__global__ void w1t_kernel(const float* __restrict__ W1, float* __restrict__ W1T)
{
    int idx = blockIdx.x * 256 + threadIdx.x;  // 65536
    int j = idx & 255, c = idx >> 8;
    W1T[j * 256 + c] = W1[c * 256 + j];
}

__global__ void mlp_kernel(const float* __restrict__ Smix, const float* __restrict__ W1T,
                           const float* __restrict__ b1, float* __restrict__ S2)
{
    int idx = blockIdx.x * 256 + threadIdx.x;  // l*256+c
    int c = idx & 255; int l = idx >> 8;
    const float* a = Smix + l * 256;
    float acc = b1[c];
    for (int j = 0; j < 256; ++j) acc += a[j] * W1T[j * 256 + c];
    float v = fmaxf(acc, 0.f);
    S2[idx] = v + a[c];
}

__global__ void y_kernel(const float* __restrict__ S2, const float* __restrict__ W2,
                         const float* __restrict__ b2, float* __restrict__ y)
{
    __shared__ float red[256];
    int l = blockIdx.x; int tid = threadIdx.x;
    red[tid] = S2[l * 256 + tid] * W2[tid];
    __syncthreads();
    for (int s = 128; s > 0; s >>= 1) { if (tid < s) red[tid] += red[tid + s]; __syncthreads(); }
    if (tid == 0) y[l] = red[0] + b2[0];
}

__global__ void norm_kernel(const float* __restrict__ y, float* __restrict__ out)
{
    __shared__ float r1[1024], r2[1024];
    int tid = threadIdx.x;
    float s1v = 0.f, s2v = 0.f;
    for (int idx = tid; idx < 2048; idx += 1024) { float v = y[idx]; s1v += v; s2v += v * v; }
    r1[tid] = s1v; r2[tid] = s2v; __syncthreads();
    for (int s = 512; s > 0; s >>= 1) {
        if (tid < s) { r1[tid] += r1[tid + s]; r2[tid] += r2[tid + s]; }
        __syncthreads();
    }
    float mean = r1[0] / 2048.f;
    float var = fmaxf((r2[0] - 2048.f * mean * mean) / 2047.f, 0.f);
    float inv = 1.f / (sqrtf(var) + 1e-8f);
    for (int idx = tid; idx < 2048; idx += 1024)
        out[idx] = (y[idx] - mean) * inv;
}

extern "C" void kernel_launch(void* const* d_in, const int* in_sizes, int n_in,
                              void* d_out, int out_size, void* d_ws, size_t ws_size,
                              hipStream_t stream)
{
    const float* x    = (const float*)d_in[0];
    const float* Wih0 = (const float*)d_in[1];
    const float* Whh0 = (const float*)d_in[2];
    const float* bih0 = (const float*)d_in[3];
    const float* bhh0 = (const float*)d_in[4];
    const float* Wih1 = (const float*)d_in[5];
    const float* Whh1 = (const float*)d_in[6];
    const float* bih1 = (const float*)d_in[7];
    const float* bhh1 = (const float*)d_in[8];
    const float* Wq   = (const float*)d_in[9];
    const float* bq   = (const float*)d_in[10];
    const float* Wk   = (const float*)d_in[11];
    const float* bk   = (const float*)d_in[12];
    const float* Wv   = (const float*)d_in[13];
    const float* bv   = (const float*)d_in[14];
    const float* R    = (const float*)d_in[15];
    const float* Wg   = (const float*)d_in[16];
    const float* bg   = (const float*)d_in[17];
    const float* W1   = (const float*)d_in[18];
    const float* b1   = (const float*)d_in[19];
    const float* W2   = (const float*)d_in[20];
    const float* b2   = (const float*)d_in[21];

    float* ws = (float*)d_ws;
    size_t off = 0;
    auto alloc_f = [&](size_t n) { float* p = ws + off; off += n; return p; };
    float* S1f  = alloc_f(524288);
    float* kh   = alloc_f(524288);
    float* vh   = alloc_f(524288);
    float* qh2  = alloc_f(524288);
    float* qhR  = alloc_f(7680);
    float* s1   = alloc_f(122880);
    float* Bm   = alloc_f(7680);
    float* kh2  = alloc_f(7680);
    float* vh2  = alloc_f(7680);
    float* Smix = alloc_f(524288);
    float* S2   = alloc_f(524288);
    float* yv   = alloc_f(2048);
    float* W1T  = alloc_f(65536);
    unsigned short* us = (unsigned short*)(ws + off);
    size_t uoff = 0;
    auto alloc_u = [&](size_t n) { unsigned short* p = us + uoff; uoff += n; return p; };
    unsigned short* H0hi[2] = { alloc_u(524288), alloc_u(524288) };
    unsigned short* H0lo[2] = { alloc_u(524288), alloc_u(524288) };
    unsigned short* H1hi[2] = { alloc_u(524288), alloc_u(524288) };
    unsigned short* H1lo[2] = { alloc_u(524288), alloc_u(524288) };
    unsigned short* FB0hi = alloc_u(245760);
    unsigned short* FB0lo = alloc_u(245760);
    unsigned short* FB1hi = alloc_u(393216);
    unsigned short* FB1lo = alloc_u(393216);
    unsigned short* FXhi  = alloc_u(16777216);
    unsigned* barp = (unsigned*)alloc_u(512);   // 256 u32: per-XCD counters at x*32
    int* xslotp = (int*)alloc_u(16);            // 8 ints: per-XCD slot claim

    pack_w<<<960, 256, 0, stream>>>(Whh0, Wih0, 64, 320, FB0hi, FB0lo, 245760);
    pack_w<<<1536, 256, 0, stream>>>(Whh1, Wih1, 256, 512, FB1hi, FB1lo, 393216);
    pack_x<<<65536, 256, 0, stream>>>(x, FXhi);
    (void)hipMemsetAsync(H0hi[0], 0, 1048576, stream);
    (void)hipMemsetAsync(H0lo[0], 0, 1048576, stream);
    (void)hipMemsetAsync(H1hi[1], 0, 1048576, stream);
    (void)hipMemsetAsync(H1lo[1], 0, 1048576, stream);
    (void)hipMemsetAsync(Bm, 0, 30720, stream);
    (void)hipMemsetAsync(barp, 0, 1024, stream);
    (void)hipMemsetAsync(xslotp, 0, 32, stream);

    gru_scan<<<256, 512, 0, stream>>>(
        H0hi[0], H0lo[0], H0hi[1], H0lo[1],
        H1hi[0], H1lo[0], H1hi[1], H1lo[1],
        FXhi, FB0hi, FB0lo, FB1hi, FB1lo,
        bih0, bhh0, bih1, bhh1, S1f, barp, xslotp);

    proj_gemm<<<192, 256, 0, stream>>>(S1f, Wk, bk, Wv, bv, Wq, bq, kh, vh, qh2);
    projR_kernel<<<30, 256, 0, stream>>>(R, Wq, bq, qhR);
    scores1_kernel<<<480, 256, 0, stream>>>(qhR, kh, s1);
    softmax1_kernel<<<60, 256, 0, stream>>>(s1);
    o1_kernel<<<960, 128, 0, stream>>>(s1, vh, Bm);
    proj3_kernel<<<60, 256, 0, stream>>>(Bm, 30, Wk, bk, Wv, bv, kh2, vh2);
    attn2_kernel<<<2048, 256, 0, stream>>>(qh2, kh2, vh2, S1f, Wg, bg, Smix);
    w1t_kernel<<<256, 256, 0, stream>>>(W1, W1T);
    mlp_kernel<<<2048, 256, 0, stream>>>(Smix, W1T, b1, S2);
    y_kernel<<<2048, 256, 0, stream>>>(S2, W2, b2, yv);
    norm_kernel<<<1, 1024, 0, stream>>>(yv, (float*)d_out);
}

// Round 5
// 1854.149 us; speedup vs baseline: 3.1920x; 1.1094x over previous
//
#include <hip/hip_runtime.h>
#include <hip/hip_bf16.h>

// CrossGRU round 10: r9 structure (XCD-local, fence-free) + VALU/latency/barrier diet.
// r9 confirmed XCD-locality: FETCH 2.46GB->32MB, 15.5us/step. Counters said the rest:
// VALUBusy 26% (libm expf/tanhf in the per-step epilogue), MfmaUtil 22% (latency slack),
// 32-wide barrier (2x the true dependency). r10: (1) raw-HW gate math (v_exp2+v_rcp
// sigmoid/tanh, clamped) ~10x fewer VALU ops; (2) A-prefetch ring-of-4 (issue kc+3,
// ~260cyc cover > 200cyc L2 latency); (3) per-row-group barrier (16 blocks: a block only
// reads H[own 128 rows][all ch] = written by its 16-block row-group; groups touch
// disjoint rows so drift is safe). Everything else identical to r9.

#define HH  256
#define TT  128
#define INP 64
#define KH  8   // h-part kc count (256/32)

typedef float f32x4 __attribute__((ext_vector_type(4)));
typedef short bf16x8 __attribute__((ext_vector_type(8)));
typedef unsigned long long u64;

#define MFMA(A,B,C) __builtin_amdgcn_mfma_f32_16x16x32_bf16((A),(B),(C),0,0,0)

__device__ __forceinline__ float bf2f(unsigned short s) {
    unsigned u = ((unsigned)s) << 16;
    float f; __builtin_memcpy(&f, &u, 4); return f;
}
__device__ __forceinline__ unsigned short f2bf(float f) {
    unsigned u; __builtin_memcpy(&u, &f, 4);
    unsigned r = (u + 0x7FFFu + ((u >> 16) & 1u)) >> 16;
    return (unsigned short)r;
}

// raw-HW gate math: v_exp_f32 (2^x) + v_rcp_f32. ~1ulp err << bf16 rounding.
// sigmoid is self-saturating (t->inf => rcp->0; t->0 => 1). tanh needs a clamp so
// (t-1)*rcp(t+1) never hits inf*0.
__device__ __forceinline__ float sigm(float x) {
    float t = __builtin_amdgcn_exp2f(x * -1.442695040889f);
    return __builtin_amdgcn_rcpf(1.f + t);
}
__device__ __forceinline__ float tanhfast(float x) {
    float xc = fminf(fmaxf(x, -15.f), 15.f);
    float t = __builtin_amdgcn_exp2f(xc * 2.885390081778f);
    return (t - 1.f) * __builtin_amdgcn_rcpf(t + 1.f);
}

// L1-bypass (sc0) 16B load as two agent-scope relaxed u64 atomic loads: reads the
// XCD-local L2 copy (fresh within the XCD), never the per-CU L1.
__device__ __forceinline__ bf16x8 ldH(const unsigned short* p) {
    union { u64 q[2]; bf16x8 v; } u;
    u.q[0] = __hip_atomic_load((u64*)p,       __ATOMIC_RELAXED, __HIP_MEMORY_SCOPE_AGENT);
    u.q[1] = __hip_atomic_load((u64*)(p + 4), __ATOMIC_RELAXED, __HIP_MEMORY_SCOPE_AGENT);
    return u.v;
}

// fragment-major index for element (row r, col k), K cols:
// idx = (r>>4)*(K*16) + (k>>5)*512 + ((k>>3)&3)*128 + (r&15)*8 + (k&7)

__global__ void pack_w(const float* __restrict__ Whh, const float* __restrict__ Wih,
                       int Kin, int Kw, unsigned short* __restrict__ FBhi,
                       unsigned short* __restrict__ FBlo, int total)
{
    int idx = blockIdx.x * 256 + threadIdx.x;
    if (idx >= total) return;
    int n = idx / Kw, k = idx - n * Kw;
    float v = (k < 256) ? Whh[n * 256 + k] : Wih[n * Kin + (k - 256)];
    int dst = (n >> 4) * (Kw * 16) + (k >> 5) * 512 + ((k >> 3) & 3) * 128 + (n & 15) * 8 + (k & 7);
    unsigned short h = f2bf(v);
    FBhi[dst] = h;
    FBlo[dst] = f2bf(v - bf2f(h));
}

__global__ void pack_x(const float* __restrict__ x, unsigned short* __restrict__ FXhi)
{
    int idx = blockIdx.x * 256 + threadIdx.x;  // 2048*128*64
    int k = idx & 63;
    int t = (idx >> 6) & 127;
    int m = idx >> 13;
    int dst = t * 131072 + (m >> 4) * 1024 + (k >> 5) * 512 + ((k >> 3) & 3) * 128 + (m & 15) * 8 + (k & 7);
    FXhi[dst] = f2bf(x[idx]);
}

// ---------------- B staging: global (frag-major, per-ntb slice) -> LDS ----------------
// LDS layout (shorts): Bhi[3][NKC*512] then Blo[3][NKC*512]
template<int NKC, int STRIDE>
__device__ __forceinline__ void stage_Bs(const unsigned short* __restrict__ Bhi,
                                         const unsigned short* __restrict__ Blo,
                                         short* __restrict__ sB, int ntb, int tid)
{
    const int Kw16 = NKC * 512;
#pragma unroll 1
    for (int t = tid; t < 3 * NKC * 64; t += STRIDE) {
        const int g = t / (NKC * 64);
        const int r = t - g * (NKC * 64);
        *(bf16x8*)(sB + g * Kw16 + r * 8) =
            *(const bf16x8*)(Bhi + (g * 16 + ntb) * Kw16 + r * 8);
        *(bf16x8*)(sB + 3 * Kw16 + g * Kw16 + r * 8) =
            *(const bf16x8*)(Blo + (g * 16 + ntb) * Kw16 + r * 8);
    }
}

// ---------------- GRU step core ----------------
// wave = 32 rows (2 m-tiles) x 16 ch (1 n-tile per gate), 3-term hi/lo MFMA.
// All B (hi+lo, all kc) from LDS. A prefetched 3 kc ahead (ring of 4, full unroll).
// H reads use ldH (sc0, L1-bypass); FX reads (LAY=false x-part) plain cached.
template<int NKC, bool LAY>
__device__ __forceinline__ void gru_core(
    const unsigned short* Ah_h, const unsigned short* Al_h,
    const unsigned short* Ah_x, const unsigned short* Al_x,
    const short* __restrict__ sB, int mt0, int lane,
    f32x4 (&ar)[2], f32x4 (&az)[2], f32x4 (&anh)[2], f32x4 (&anx)[2])
{
    const int Kw16 = NKC * 512;            // Kw*16
    const int xs = LAY ? 4096 : 1024;      // x-source per-m-tile stride
    const int lo8 = lane * 8;
    const short* sH = sB + lo8;
    const short* sL = sB + 3 * Kw16 + lo8;

    bf16x8 A[4][2][2];                     // ring of 4; indices const after full unroll
    bf16x8 cB[3][2], nB[3][2];

    auto ldA = [&](int kc, bf16x8 (&Ax)[2][2]) {
        if (kc < KH) {
#pragma unroll
            for (int mt = 0; mt < 2; ++mt) {
                Ax[mt][0] = ldH(Ah_h + (mt0 + mt) * 4096 + kc * 512 + lo8);
                Ax[mt][1] = ldH(Al_h + (mt0 + mt) * 4096 + kc * 512 + lo8);
            }
        } else {
#pragma unroll
            for (int mt = 0; mt < 2; ++mt) {
                if (LAY) {
                    Ax[mt][0] = ldH(Ah_x + (mt0 + mt) * xs + (kc - KH) * 512 + lo8);
                    Ax[mt][1] = ldH(Al_x + (mt0 + mt) * xs + (kc - KH) * 512 + lo8);
                } else {
                    Ax[mt][0] = *(const bf16x8*)(Ah_x + (mt0 + mt) * xs + (kc - KH) * 512 + lo8);
                }
            }
        }
    };
    auto ldB = [&](int kc, bf16x8 (&B)[3][2]) {
#pragma unroll
        for (int g = 0; g < 3; ++g) {
            B[g][0] = *(const bf16x8*)(sH + g * Kw16 + kc * 512);
            B[g][1] = *(const bf16x8*)(sL + g * Kw16 + kc * 512);
        }
    };

    ldA(0, A[0]);
    if (NKC > 1) ldA(1, A[1]);
    if (NKC > 2) ldA(2, A[2]);
    ldB(0, cB);
#pragma unroll
    for (int kc = 0; kc < NKC; ++kc) {
        if (kc + 3 < NKC) ldA(kc + 3, A[(kc + 3) & 3]);
        if (kc + 1 < NKC) ldB(kc + 1, nB);
        const bool hp = (kc < KH);
        const bool a3 = LAY || hp;     // 3rd (a_lo) term availability
        bf16x8 (&cA)[2][2] = A[kc & 3];
#pragma unroll
        for (int mt = 0; mt < 2; ++mt) {
            ar[mt] = MFMA(cA[mt][0], cB[0][0], ar[mt]);
            ar[mt] = MFMA(cA[mt][0], cB[0][1], ar[mt]);
            if (a3) ar[mt] = MFMA(cA[mt][1], cB[0][0], ar[mt]);
            az[mt] = MFMA(cA[mt][0], cB[1][0], az[mt]);
            az[mt] = MFMA(cA[mt][0], cB[1][1], az[mt]);
            if (a3) az[mt] = MFMA(cA[mt][1], cB[1][0], az[mt]);
            if (hp) {
                anh[mt] = MFMA(cA[mt][0], cB[2][0], anh[mt]);
                anh[mt] = MFMA(cA[mt][0], cB[2][1], anh[mt]);
                if (a3) anh[mt] = MFMA(cA[mt][1], cB[2][0], anh[mt]);
            } else {
                anx[mt] = MFMA(cA[mt][0], cB[2][0], anx[mt]);
                anx[mt] = MFMA(cA[mt][0], cB[2][1], anx[mt]);
                if (a3) anx[mt] = MFMA(cA[mt][1], cB[2][0], anx[mt]);
            }
        }
#pragma unroll
        for (int g = 0; g < 3; ++g) { cB[g][0] = nB[g][0]; cB[g][1] = nB[g][1]; }
    }
}

// Per-row-group barrier: 16 blocks on one counter. No fences: stores drained by the
// pre-barrier syncthreads (write-through L1 -> local L2); readers use sc0 loads.
__device__ __forceinline__ void xcd_bar(unsigned* cnt, unsigned need)
{
    __syncthreads();
    if (threadIdx.x == 0) {
        __hip_atomic_fetch_add(cnt, 1u, __ATOMIC_RELAXED, __HIP_MEMORY_SCOPE_AGENT);
        while (__hip_atomic_load(cnt, __ATOMIC_RELAXED, __HIP_MEMORY_SCOPE_AGENT) < need)
            __builtin_amdgcn_s_sleep(1);
    }
    __syncthreads();
    asm volatile("" ::: "memory");
}

// Persistent scan: 256 blocks x 512 threads, 1 block/CU (156KB LDS) -> each XCD hosts
// exactly 32 blocks (pigeonhole). Block claims (row-half, ch-tile) within ITS OWN XCD.
// Sync group = 16 blocks sharing (xcc, row-half): a block reads H[own rows][all ch],
// written only by those 16. Row-groups touch disjoint rows -> drift-safe.
// Waves 0-3: layer0 step i; waves 4-7: layer1 step i-1.
__global__ __launch_bounds__(512, 2) void gru_scan(
    unsigned short* H0hiA, unsigned short* H0loA,
    unsigned short* H0hiB, unsigned short* H0loB,
    unsigned short* H1hiA, unsigned short* H1loA,
    unsigned short* H1hiB, unsigned short* H1loB,
    const unsigned short* __restrict__ FXhi,
    const unsigned short* __restrict__ FB0hi, const unsigned short* __restrict__ FB0lo,
    const unsigned short* __restrict__ FB1hi, const unsigned short* __restrict__ FB1lo,
    const float* __restrict__ bih0, const float* __restrict__ bhh0,
    const float* __restrict__ bih1, const float* __restrict__ bhh1,
    float* __restrict__ S1f, unsigned* bar, int* xslot)
{
    const int tid = threadIdx.x;
    int xcc;
    asm volatile("s_getreg_b32 %0, hwreg(HW_REG_XCC_ID)" : "=s"(xcc));
    xcc &= 7;
    __shared__ int sSlot;
    if (tid == 0) sSlot = atomicAdd(&xslot[xcc], 1) & 31;   // device-scope claim
    __syncthreads();
    const int slot = sSlot;           // 0..31 within this XCD
    const int mb2 = slot >> 4;        // row-half (128 rows) of the XCD's 256 rows
    const int cb = slot & 15;         // 16-ch tile within gate
    const int w = tid >> 6, lane = tid & 63;
    const int lay = w >> 2, wl = w & 3;
    const int l15 = lane & 15, q = lane >> 4;
    const int mt0 = xcc * 16 + mb2 * 8 + wl * 2;  // first 16-row tile (of 128)
    const int ntb = cb;
    unsigned* cnt = bar + (xcc * 2 + mb2) * 32;   // per-row-group counter, 128B apart

    // sB1: (hi+lo)[3][16*512] = 49152 shorts (96KB); sB0: (hi+lo)[3][10*512] = 30720 (60KB)
    __shared__ __align__(16) short sB[79872];
    short* sB1 = sB;
    short* sB0 = sB + 49152;
    stage_Bs<16, 512>(FB1hi, FB1lo, sB1, cb, tid);
    stage_Bs<10, 512>(FB0hi, FB0lo, sB0, cb, tid);
    __syncthreads();

    // per-thread epilogue constants (hoisted out of the scan loop)
    const float* bih = lay ? bih1 : bih0;
    const float* bhh = lay ? bhh1 : bhh0;
    const int c = (ntb << 4) + l15;   // channel 0..255
    const float brb = bih[c] + bhh[c];
    const float bzb = bih[256 + c] + bhh[256 + c];
    const float bni = bih[512 + c];
    const float bnh = bhh[512 + c];
    const int cfr = (c >> 5) * 512 + ((c >> 3) & 3) * 128 + (c & 7);

    for (int i = 0; i <= TT; ++i) {
        const int p = i & 1;
        const unsigned short* H0r_hi = p ? H0hiB : H0hiA;
        const unsigned short* H0r_lo = p ? H0loB : H0loA;
        unsigned short*       H0w_hi = p ? H0hiA : H0hiB;
        unsigned short*       H0w_lo = p ? H0loA : H0loB;
        const unsigned short* H1r_hi = p ? H1hiB : H1hiA;
        const unsigned short* H1r_lo = p ? H1loB : H1loA;
        unsigned short*       H1w_hi = p ? H1hiA : H1hiB;
        unsigned short*       H1w_lo = p ? H1loA : H1loB;

        const bool active = lay ? (i >= 1) : (i < TT);
        if (active) {
            f32x4 ar[2], az[2], anh[2], anx[2];
#pragma unroll
            for (int j = 0; j < 2; ++j) {
                ar[j] = (f32x4){0.f,0.f,0.f,0.f}; az[j] = (f32x4){0.f,0.f,0.f,0.f};
                anh[j] = (f32x4){0.f,0.f,0.f,0.f}; anx[j] = (f32x4){0.f,0.f,0.f,0.f};
            }
            if (lay) {
                gru_core<16, true>(H1r_hi, H1r_lo, H0r_hi, H0r_lo, sB1,
                                   mt0, lane, ar, az, anh, anx);
            } else {
                gru_core<10, false>(H0r_hi, H0r_lo, FXhi + i * 131072,
                                    (const unsigned short*)0, sB0,
                                    mt0, lane, ar, az, anh, anx);
            }

            const unsigned short* Ahi_h = lay ? H1r_hi : H0r_hi;
            const unsigned short* Alo_h = lay ? H1r_lo : H0r_lo;
            unsigned short* Whi = lay ? H1w_hi : H0w_hi;
            unsigned short* Wlo = lay ? H1w_lo : H0w_lo;

#pragma unroll
            for (int mt = 0; mt < 2; ++mt) {
                const int mtg = mt0 + mt;
                const int fbase = mtg * 4096 + cfr;
#pragma unroll
                for (int rg = 0; rg < 4; ++rg) {
                    const int mi = q * 4 + rg;
                    const int fidx = fbase + mi * 8;
                    const float ho = bf2f(Ahi_h[fidx]) + bf2f(Alo_h[fidx]);
                    const float rr = sigm(ar[mt][rg] + brb);
                    const float zz = sigm(az[mt][rg] + bzb);
                    const float nn = tanhfast(anx[mt][rg] + bni + rr * (anh[mt][rg] + bnh));
                    const float hn = (1.f - zz) * nn + zz * ho;
                    const unsigned short hb = f2bf(hn);
                    Whi[fidx] = hb;
                    Wlo[fidx] = f2bf(hn - bf2f(hb));
                    if (lay && i == TT) S1f[(mtg * 16 + mi) * 256 + c] = hn;
                }
            }
        }
        if (i < TT) xcd_bar(cnt, 16u * (unsigned)(i + 1));
    }
}

// ---------------- epilogue ----------------

__global__ __launch_bounds__(256) void proj_gemm(const float* __restrict__ S,
    const float* __restrict__ Wk, const float* __restrict__ bk,
    const float* __restrict__ Wv, const float* __restrict__ bv,
    const float* __restrict__ Wq, const float* __restrict__ bq,
    float* __restrict__ ok, float* __restrict__ ov, float* __restrict__ oq)
{
    __shared__ float sT[256][65];
    const int bid = blockIdx.x;            // 192 = 3p * 2h * 32lt
    const int p = bid >> 6;
    const int h = (bid >> 5) & 1;
    const int l0 = (bid & 31) * 64;
    const int tid = threadIdx.x;
    const float* W = (p == 0) ? Wk : ((p == 1) ? Wv : Wq);
    const float* b = (p == 0) ? bk : ((p == 1) ? bv : bq);
    float* o = (p == 0) ? ok : ((p == 1) ? ov : oq);

    for (int e = tid; e < 64 * 256; e += 256) {
        int k = e & 255, l = e >> 8;
        sT[k][l] = S[(l0 + l) * 256 + k];
    }
    __syncthreads();

    const int dg = tid & 15, lg = tid >> 4;
    const int d0 = dg * 8;
    const float* Wp = W + h * 32768 + d0;
    float acc[4][8];
#pragma unroll
    for (int i = 0; i < 4; ++i)
#pragma unroll
        for (int j = 0; j < 8; ++j) acc[i][j] = 0.f;

    for (int k = 0; k < 256; ++k) {
        f32x4 sv = *(const f32x4*)&sT[k][lg * 4];
        f32x4 w0 = *(const f32x4*)(Wp + k * 128);
        f32x4 w1 = *(const f32x4*)(Wp + k * 128 + 4);
#pragma unroll
        for (int i = 0; i < 4; ++i) {
#pragma unroll
            for (int j = 0; j < 4; ++j) {
                acc[i][j]     += sv[i] * w0[j];
                acc[i][4 + j] += sv[i] * w1[j];
            }
        }
    }
#pragma unroll
    for (int i = 0; i < 4; ++i) {
        float* op = o + (h * 2048 + l0 + lg * 4 + i) * 128 + d0;
#pragma unroll
        for (int j = 0; j < 8; ++j) op[j] = acc[i][j] + b[h * 128 + d0 + j];
    }
}

__global__ void proj3_kernel(const float* __restrict__ A, int M,
    const float* __restrict__ Wk, const float* __restrict__ bk,
    const float* __restrict__ Wv, const float* __restrict__ bv,
    float* __restrict__ ok, float* __restrict__ ov)
{
    int idx = blockIdx.x * 256 + threadIdx.x;
    if (idx >= 2 * 2 * M * 128) return;
    int d = idx & 127;
    int rest = idx >> 7;
    int l = rest % M;
    int ph = rest / M;
    int h = ph & 1, p = ph >> 1;
    const float* W = (p == 0) ? Wk : Wv;
    const float* b = (p == 0) ? bk : bv;
    float* o = (p == 0) ? ok : ov;
    float accv = b[h * 128 + d];
    const float* a = A + l * 256;
    const float* wp = W + h * (256 * 128) + d;
    for (int j = 0; j < 256; ++j) accv += a[j] * wp[j * 128];
    o[(h * M + l) * 128 + d] = accv;
}

__global__ void projR_kernel(const float* __restrict__ R,
    const float* __restrict__ Wq, const float* __restrict__ bq,
    float* __restrict__ oq)
{
    int idx = blockIdx.x * 256 + threadIdx.x;
    if (idx >= 2 * 30 * 128) return;
    int d = idx & 127;
    int rest = idx >> 7;
    int l = rest % 30;
    int h = rest / 30;
    float a = bq[h * 128 + d];
    const float* r = R + l * 256;
    const float* wp = Wq + h * 32768 + d;
    for (int j = 0; j < 256; ++j) a += r[j] * wp[j * 128];
    oq[(h * 30 + l) * 128 + d] = a;
}

__global__ void scores1_kernel(const float* __restrict__ qhR, const float* __restrict__ kh,
                               float* __restrict__ s1)
{
    int idx = blockIdx.x * 256 + threadIdx.x;
    if (idx >= 2 * 30 * 2048) return;
    int k = idx & 2047;
    int rest = idx >> 11;
    int i = rest % 30;
    int h = rest / 30;
    const f32x4* qp = (const f32x4*)(qhR + (h * 30 + i) * 128);
    const f32x4* kp = (const f32x4*)(kh + (h * 2048 + k) * 128);
    float acc = 0.f;
    for (int dd = 0; dd < 32; ++dd) {
        f32x4 a = qp[dd], b = kp[dd];
        acc += a[0] * b[0] + a[1] * b[1] + a[2] * b[2] + a[3] * b[3];
    }
    s1[idx] = acc * 0.08838834764831845f;
}

__global__ void softmax1_kernel(float* __restrict__ s1)
{
    __shared__ float red[256];
    float* p = s1 + blockIdx.x * 2048;
    int tid = threadIdx.x;
    float mx = -1e30f;
    for (int k = tid; k < 2048; k += 256) mx = fmaxf(mx, p[k]);
    red[tid] = mx; __syncthreads();
    for (int s = 128; s > 0; s >>= 1) { if (tid < s) red[tid] = fmaxf(red[tid], red[tid + s]); __syncthreads(); }
    mx = red[0]; __syncthreads();
    float sum = 0.f;
    for (int k = tid; k < 2048; k += 256) { float e = expf(p[k] - mx); p[k] = e; sum += e; }
    red[tid] = sum; __syncthreads();
    for (int s = 128; s > 0; s >>= 1) { if (tid < s) red[tid] += red[tid + s]; __syncthreads(); }
    float inv = 1.f / red[0];
    for (int k = tid; k < 2048; k += 256) p[k] *= inv;
}

// split-K o1: 16 k-slices per output row, fp32 atomicAdd into zeroed Bm.
__global__ void o1_kernel(const float* __restrict__ p1, const float* __restrict__ vh,
                          float* __restrict__ Bm)
{
    int bid = blockIdx.x;            // 60 rows * 16 k-slices
    int row = bid >> 4;              // h*30+i
    int ks = bid & 15;
    int h = row / 30;
    int i = row % 30;
    int d = threadIdx.x;             // 128
    const float* pp = p1 + row * 2048 + ks * 128;
    const float* vp = vh + (h * 2048 + ks * 128) * 128 + d;
    float acc = 0.f;
    for (int k = 0; k < 128; ++k) acc += pp[k] * vp[k * 128];
    atomicAdd(&Bm[i * 256 + h * 128 + d], acc);
}

__global__ __launch_bounds__(256) void attn2_kernel(
    const float* __restrict__ qh2, const float* __restrict__ kh2, const float* __restrict__ vh2,
    const float* __restrict__ S, const float* __restrict__ Wg,
    const float* __restrict__ bg, float* __restrict__ Smix)
{
    __shared__ float ks[2 * 30 * 129];
    __shared__ float qred[256];
    __shared__ float ps[64];
    int l = blockIdx.x;
    int tid = threadIdx.x;
    for (int idx = tid; idx < 2 * 30 * 128; idx += 256) {
        int hh = idx / 3840; int rem = idx - hh * 3840;
        int j = rem >> 7; int d = rem & 127;
        ks[(hh * 30 + j) * 129 + d] = kh2[idx];
    }
    int h = tid >> 7, d = tid & 127;
    qred[tid] = qh2[(h * 2048 + l) * 128 + d];
    __syncthreads();
    int w = tid >> 6, lane = tid & 63;
    if (w < 2 && lane < 32) {
        float sc = -1e30f;
        if (lane < 30) {
            const float* qp = qred + w * 128;
            float a = 0.f;
            for (int dd = 0; dd < 128; ++dd) a += qp[dd] * ks[(w * 30 + lane) * 129 + dd];
            sc = a * 0.08838834764831845f;
        }
        float mx = sc;
        for (int m = 16; m > 0; m >>= 1) mx = fmaxf(mx, __shfl_xor(mx, m, 32));
        float e = (lane < 30) ? expf(sc - mx) : 0.f;
        float sm = e;
        for (int m = 16; m > 0; m >>= 1) sm += __shfl_xor(sm, m, 32);
        ps[w * 32 + lane] = e / sm;
    }
    __syncthreads();
    float o = 0.f;
    const float* vp = vh2 + h * 3840 + d;
    for (int j = 0; j < 30; ++j) o += ps[h * 32 + j] * vp[j * 128];
    float sl = S[l * 256 + tid];
    qred[tid] = sl * Wg[tid];
    __syncthreads();
    for (int s = 128; s > 0; s >>= 1) { if (tid < s) qred[tid] += qred[tid + s]; __syncthreads(); }
    float alpha = 1.f / (1.f + expf(-(qred[0] + bg[0])));
    Smix[l * 256 + tid] = alpha * o + (1.f - alpha) * sl;
}

__global__ void w1t_kernel(const float* __restrict__ W1, float* __restrict__ W1T)
{
    int idx = blockIdx.x * 256 + threadIdx.x;  // 65536
    int j = idx & 255, c = idx >> 8;
    W1T[j * 256 + c] = W1[c * 256 + j];
}

__global__ void mlp_kernel(const float* __restrict__ Smix, const float* __restrict__ W1T,
                           const float* __restrict__ b1, float* __restrict__ S2)
{
    int idx = blockIdx.x * 256 + threadIdx.x;  // l*256+c
    int c = idx & 255; int l = idx >> 8;
    const float* a = Smix + l * 256;
    float acc = b1[c];
    for (int j = 0; j < 256; ++j) acc += a[j] * W1T[j * 256 + c];
    float v = fmaxf(acc, 0.f);
    S2[idx] = v + a[c];
}

__global__ void y_kernel(const float* __restrict__ S2, const float* __restrict__ W2,
                         const float* __restrict__ b2, float* __restrict__ y)
{
    __shared__ float red[256];
    int l = blockIdx.x; int tid = threadIdx.x;
    red[tid] = S2[l * 256 + tid] * W2[tid];
    __syncthreads();
    for (int s = 128; s > 0; s >>= 1) { if (tid < s) red[tid] += red[tid + s]; __syncthreads(); }
    if (tid == 0) y[l] = red[0] + b2[0];
}

__global__ void norm_kernel(const float* __restrict__ y, float* __restrict__ out)
{
    __shared__ float r1[1024], r2[1024];
    int tid = threadIdx.x;
    float s1v = 0.f, s2v = 0.f;
    for (int idx = tid; idx < 2048; idx += 1024) { float v = y[idx]; s1v += v; s2v += v * v; }
    r1[tid] = s1v; r2[tid] = s2v; __syncthreads();
    for (int s = 512; s > 0; s >>= 1) {
        if (tid < s) { r1[tid] += r1[tid + s]; r2[tid] += r2[tid + s]; }
        __syncthreads();
    }
    float mean = r1[0] / 2048.f;
    float var = fmaxf((r2[0] - 2048.f * mean * mean) / 2047.f, 0.f);
    float inv = 1.f / (sqrtf(var) + 1e-8f);
    for (int idx = tid; idx < 2048; idx += 1024)
        out[idx] = (y[idx] - mean) * inv;
}

extern "C" void kernel_launch(void* const* d_in, const int* in_sizes, int n_in,
                              void* d_out, int out_size, void* d_ws, size_t ws_size,
                              hipStream_t stream)
{
    const float* x    = (const float*)d_in[0];
    const float* Wih0 = (const float*)d_in[1];
    const float* Whh0 = (const float*)d_in[2];
    const float* bih0 = (const float*)d_in[3];
    const float* bhh0 = (const float*)d_in[4];
    const float* Wih1 = (const float*)d_in[5];
    const float* Whh1 = (const float*)d_in[6];
    const float* bih1 = (const float*)d_in[7];
    const float* bhh1 = (const float*)d_in[8];
    const float* Wq   = (const float*)d_in[9];
    const float* bq   = (const float*)d_in[10];
    const float* Wk   = (const float*)d_in[11];
    const float* bk   = (const float*)d_in[12];
    const float* Wv   = (const float*)d_in[13];
    const float* bv   = (const float*)d_in[14];
    const float* R    = (const float*)d_in[15];
    const float* Wg   = (const float*)d_in[16];
    const float* bg   = (const float*)d_in[17];
    const float* W1   = (const float*)d_in[18];
    const float* b1   = (const float*)d_in[19];
    const float* W2   = (const float*)d_in[20];
    const float* b2   = (const float*)d_in[21];

    float* ws = (float*)d_ws;
    size_t off = 0;
    auto alloc_f = [&](size_t n) { float* p = ws + off; off += n; return p; };
    float* S1f  = alloc_f(524288);
    float* kh   = alloc_f(524288);
    float* vh   = alloc_f(524288);
    float* qh2  = alloc_f(524288);
    float* qhR  = alloc_f(7680);
    float* s1   = alloc_f(122880);
    float* Bm   = alloc_f(7680);
    float* kh2  = alloc_f(7680);
    float* vh2  = alloc_f(7680);
    float* Smix = alloc_f(524288);
    float* S2   = alloc_f(524288);
    float* yv   = alloc_f(2048);
    float* W1T  = alloc_f(65536);
    unsigned short* us = (unsigned short*)(ws + off);
    size_t uoff = 0;
    auto alloc_u = [&](size_t n) { unsigned short* p = us + uoff; uoff += n; return p; };
    unsigned short* H0hi[2] = { alloc_u(524288), alloc_u(524288) };
    unsigned short* H0lo[2] = { alloc_u(524288), alloc_u(524288) };
    unsigned short* H1hi[2] = { alloc_u(524288), alloc_u(524288) };
    unsigned short* H1lo[2] = { alloc_u(524288), alloc_u(524288) };
    unsigned short* FB0hi = alloc_u(245760);
    unsigned short* FB0lo = alloc_u(245760);
    unsigned short* FB1hi = alloc_u(393216);
    unsigned short* FB1lo = alloc_u(393216);
    unsigned short* FXhi  = alloc_u(16777216);
    unsigned* barp = (unsigned*)alloc_u(1024);  // 512 u32: per-row-group counters at (x*2+g)*32
    int* xslotp = (int*)alloc_u(16);            // 8 ints: per-XCD slot claim

    pack_w<<<960, 256, 0, stream>>>(Whh0, Wih0, 64, 320, FB0hi, FB0lo, 245760);
    pack_w<<<1536, 256, 0, stream>>>(Whh1, Wih1, 256, 512, FB1hi, FB1lo, 393216);
    pack_x<<<65536, 256, 0, stream>>>(x, FXhi);
    (void)hipMemsetAsync(H0hi[0], 0, 1048576, stream);
    (void)hipMemsetAsync(H0lo[0], 0, 1048576, stream);
    (void)hipMemsetAsync(H1hi[1], 0, 1048576, stream);
    (void)hipMemsetAsync(H1lo[1], 0, 1048576, stream);
    (void)hipMemsetAsync(Bm, 0, 30720, stream);
    (void)hipMemsetAsync(barp, 0, 2048, stream);
    (void)hipMemsetAsync(xslotp, 0, 32, stream);

    gru_scan<<<256, 512, 0, stream>>>(
        H0hi[0], H0lo[0], H0hi[1], H0lo[1],
        H1hi[0], H1lo[0], H1hi[1], H1lo[1],
        FXhi, FB0hi, FB0lo, FB1hi, FB1lo,
        bih0, bhh0, bih1, bhh1, S1f, barp, xslotp);

    proj_gemm<<<192, 256, 0, stream>>>(S1f, Wk, bk, Wv, bv, Wq, bq, kh, vh, qh2);
    projR_kernel<<<30, 256, 0, stream>>>(R, Wq, bq, qhR);
    scores1_kernel<<<480, 256, 0, stream>>>(qhR, kh, s1);
    softmax1_kernel<<<60, 256, 0, stream>>>(s1);
    o1_kernel<<<960, 128, 0, stream>>>(s1, vh, Bm);
    proj3_kernel<<<60, 256, 0, stream>>>(Bm, 30, Wk, bk, Wv, bv, kh2, vh2);
    attn2_kernel<<<2048, 256, 0, stream>>>(qh2, kh2, vh2, S1f, Wg, bg, Smix);
    w1t_kernel<<<256, 256, 0, stream>>>(W1, W1T);
    mlp_kernel<<<2048, 256, 0, stream>>>(Smix, W1T, b1, S2);
    y_kernel<<<2048, 256, 0, stream>>>(S2, W2, b2, yv);
    norm_kernel<<<1, 1024, 0, stream>>>(yv, (float*)d_out);
}

// Round 6
// 1770.921 us; speedup vs baseline: 3.3420x; 1.0470x over previous
//
#include <hip/hip_runtime.h>
#include <hip/hip_bf16.h>

// CrossGRU round 11: r10 structure + serial-tail removal.
// r10: 13.7us/step, VALUBusy 16%, MfmaUtil 24.5%, FETCH 32MB (XCD-locality intact).
// Two serial tails removed: (1) epilogue re-loaded H_old as 16 scalar u16 global loads
// per thread per step — but the (row,ch) a thread writes is step-invariant, so H_old
// lives in registers now (rounding replicated exactly: ho_next=bf2f(hb)+bf2f(lb));
// (2) LDS B-prefetch deepened to distance 2 (ring-of-3, static indices). Everything
// else (XCD-local sc0 H loads, per-row-group 16-block barrier, all-B-in-LDS) identical.

#define HH  256
#define TT  128
#define INP 64
#define KH  8   // h-part kc count (256/32)

typedef float f32x4 __attribute__((ext_vector_type(4)));
typedef short bf16x8 __attribute__((ext_vector_type(8)));
typedef unsigned long long u64;

#define MFMA(A,B,C) __builtin_amdgcn_mfma_f32_16x16x32_bf16((A),(B),(C),0,0,0)

__device__ __forceinline__ float bf2f(unsigned short s) {
    unsigned u = ((unsigned)s) << 16;
    float f; __builtin_memcpy(&f, &u, 4); return f;
}
__device__ __forceinline__ unsigned short f2bf(float f) {
    unsigned u; __builtin_memcpy(&u, &f, 4);
    unsigned r = (u + 0x7FFFu + ((u >> 16) & 1u)) >> 16;
    return (unsigned short)r;
}

// raw-HW gate math: v_exp_f32 (2^x) + v_rcp_f32. ~1ulp err << bf16 rounding.
__device__ __forceinline__ float sigm(float x) {
    float t = __builtin_amdgcn_exp2f(x * -1.442695040889f);
    return __builtin_amdgcn_rcpf(1.f + t);
}
__device__ __forceinline__ float tanhfast(float x) {
    float xc = fminf(fmaxf(x, -15.f), 15.f);
    float t = __builtin_amdgcn_exp2f(xc * 2.885390081778f);
    return (t - 1.f) * __builtin_amdgcn_rcpf(t + 1.f);
}

// L1-bypass (sc0) 16B load as two agent-scope relaxed u64 atomic loads: reads the
// XCD-local L2 copy (fresh within the XCD), never the per-CU L1.
__device__ __forceinline__ bf16x8 ldH(const unsigned short* p) {
    union { u64 q[2]; bf16x8 v; } u;
    u.q[0] = __hip_atomic_load((u64*)p,       __ATOMIC_RELAXED, __HIP_MEMORY_SCOPE_AGENT);
    u.q[1] = __hip_atomic_load((u64*)(p + 4), __ATOMIC_RELAXED, __HIP_MEMORY_SCOPE_AGENT);
    return u.v;
}

// fragment-major index for element (row r, col k), K cols:
// idx = (r>>4)*(K*16) + (k>>5)*512 + ((k>>3)&3)*128 + (r&15)*8 + (k&7)

__global__ void pack_w(const float* __restrict__ Whh, const float* __restrict__ Wih,
                       int Kin, int Kw, unsigned short* __restrict__ FBhi,
                       unsigned short* __restrict__ FBlo, int total)
{
    int idx = blockIdx.x * 256 + threadIdx.x;
    if (idx >= total) return;
    int n = idx / Kw, k = idx - n * Kw;
    float v = (k < 256) ? Whh[n * 256 + k] : Wih[n * Kin + (k - 256)];
    int dst = (n >> 4) * (Kw * 16) + (k >> 5) * 512 + ((k >> 3) & 3) * 128 + (n & 15) * 8 + (k & 7);
    unsigned short h = f2bf(v);
    FBhi[dst] = h;
    FBlo[dst] = f2bf(v - bf2f(h));
}

__global__ void pack_x(const float* __restrict__ x, unsigned short* __restrict__ FXhi)
{
    int idx = blockIdx.x * 256 + threadIdx.x;  // 2048*128*64
    int k = idx & 63;
    int t = (idx >> 6) & 127;
    int m = idx >> 13;
    int dst = t * 131072 + (m >> 4) * 1024 + (k >> 5) * 512 + ((k >> 3) & 3) * 128 + (m & 15) * 8 + (k & 7);
    FXhi[dst] = f2bf(x[idx]);
}

// ---------------- B staging: global (frag-major, per-ntb slice) -> LDS ----------------
// LDS layout (shorts): Bhi[3][NKC*512] then Blo[3][NKC*512]
template<int NKC, int STRIDE>
__device__ __forceinline__ void stage_Bs(const unsigned short* __restrict__ Bhi,
                                         const unsigned short* __restrict__ Blo,
                                         short* __restrict__ sB, int ntb, int tid)
{
    const int Kw16 = NKC * 512;
#pragma unroll 1
    for (int t = tid; t < 3 * NKC * 64; t += STRIDE) {
        const int g = t / (NKC * 64);
        const int r = t - g * (NKC * 64);
        *(bf16x8*)(sB + g * Kw16 + r * 8) =
            *(const bf16x8*)(Bhi + (g * 16 + ntb) * Kw16 + r * 8);
        *(bf16x8*)(sB + 3 * Kw16 + g * Kw16 + r * 8) =
            *(const bf16x8*)(Blo + (g * 16 + ntb) * Kw16 + r * 8);
    }
}

// ---------------- GRU step core ----------------
// wave = 32 rows (2 m-tiles) x 16 ch (1 n-tile per gate), 3-term hi/lo MFMA.
// All B (hi+lo, all kc) from LDS, prefetched 2 kc ahead (ring of 3).
// A prefetched 3 kc ahead (ring of 4). All ring indices static after full unroll.
template<int NKC, bool LAY>
__device__ __forceinline__ void gru_core(
    const unsigned short* Ah_h, const unsigned short* Al_h,
    const unsigned short* Ah_x, const unsigned short* Al_x,
    const short* __restrict__ sB, int mt0, int lane,
    f32x4 (&ar)[2], f32x4 (&az)[2], f32x4 (&anh)[2], f32x4 (&anx)[2])
{
    const int Kw16 = NKC * 512;            // Kw*16
    const int xs = LAY ? 4096 : 1024;      // x-source per-m-tile stride
    const int lo8 = lane * 8;
    const short* sH = sB + lo8;
    const short* sL = sB + 3 * Kw16 + lo8;

    bf16x8 A[4][2][2];                     // ring of 4
    bf16x8 B[3][3][2];                     // ring of 3: [slot][gate][hi/lo]

    auto ldA = [&](int kc, bf16x8 (&Ax)[2][2]) {
        if (kc < KH) {
#pragma unroll
            for (int mt = 0; mt < 2; ++mt) {
                Ax[mt][0] = ldH(Ah_h + (mt0 + mt) * 4096 + kc * 512 + lo8);
                Ax[mt][1] = ldH(Al_h + (mt0 + mt) * 4096 + kc * 512 + lo8);
            }
        } else {
#pragma unroll
            for (int mt = 0; mt < 2; ++mt) {
                if (LAY) {
                    Ax[mt][0] = ldH(Ah_x + (mt0 + mt) * xs + (kc - KH) * 512 + lo8);
                    Ax[mt][1] = ldH(Al_x + (mt0 + mt) * xs + (kc - KH) * 512 + lo8);
                } else {
                    Ax[mt][0] = *(const bf16x8*)(Ah_x + (mt0 + mt) * xs + (kc - KH) * 512 + lo8);
                }
            }
        }
    };
    auto ldB = [&](int kc, bf16x8 (&Bx)[3][2]) {
#pragma unroll
        for (int g = 0; g < 3; ++g) {
            Bx[g][0] = *(const bf16x8*)(sH + g * Kw16 + kc * 512);
            Bx[g][1] = *(const bf16x8*)(sL + g * Kw16 + kc * 512);
        }
    };

    ldA(0, A[0]);
    if (NKC > 1) ldA(1, A[1]);
    if (NKC > 2) ldA(2, A[2]);
    ldB(0, B[0]);
    if (NKC > 1) ldB(1, B[1]);
#pragma unroll
    for (int kc = 0; kc < NKC; ++kc) {
        if (kc + 3 < NKC) ldA(kc + 3, A[(kc + 3) & 3]);
        if (kc + 2 < NKC) ldB(kc + 2, B[(kc + 2) % 3]);
        const bool hp = (kc < KH);
        const bool a3 = LAY || hp;     // 3rd (a_lo) term availability
        bf16x8 (&cA)[2][2] = A[kc & 3];
        bf16x8 (&cB)[3][2] = B[kc % 3];
#pragma unroll
        for (int mt = 0; mt < 2; ++mt) {
            ar[mt] = MFMA(cA[mt][0], cB[0][0], ar[mt]);
            ar[mt] = MFMA(cA[mt][0], cB[0][1], ar[mt]);
            if (a3) ar[mt] = MFMA(cA[mt][1], cB[0][0], ar[mt]);
            az[mt] = MFMA(cA[mt][0], cB[1][0], az[mt]);
            az[mt] = MFMA(cA[mt][0], cB[1][1], az[mt]);
            if (a3) az[mt] = MFMA(cA[mt][1], cB[1][0], az[mt]);
            if (hp) {
                anh[mt] = MFMA(cA[mt][0], cB[2][0], anh[mt]);
                anh[mt] = MFMA(cA[mt][0], cB[2][1], anh[mt]);
                if (a3) anh[mt] = MFMA(cA[mt][1], cB[2][0], anh[mt]);
            } else {
                anx[mt] = MFMA(cA[mt][0], cB[2][0], anx[mt]);
                anx[mt] = MFMA(cA[mt][0], cB[2][1], anx[mt]);
                if (a3) anx[mt] = MFMA(cA[mt][1], cB[2][0], anx[mt]);
            }
        }
    }
}

// Per-row-group barrier: 16 blocks on one counter. No fences: stores drained by the
// pre-barrier syncthreads (write-through L1 -> local L2); readers use sc0 loads.
__device__ __forceinline__ void xcd_bar(unsigned* cnt, unsigned need)
{
    __syncthreads();
    if (threadIdx.x == 0) {
        __hip_atomic_fetch_add(cnt, 1u, __ATOMIC_RELAXED, __HIP_MEMORY_SCOPE_AGENT);
        while (__hip_atomic_load(cnt, __ATOMIC_RELAXED, __HIP_MEMORY_SCOPE_AGENT) < need)
            __builtin_amdgcn_s_sleep(1);
    }
    __syncthreads();
    asm volatile("" ::: "memory");
}

// Persistent scan: 256 blocks x 512 threads, 1 block/CU (156KB LDS) -> each XCD hosts
// exactly 32 blocks (pigeonhole). Block claims (row-half, ch-tile) within ITS OWN XCD.
// Sync group = 16 blocks sharing (xcc, row-half). Waves 0-3: L0 step i; 4-7: L1 step i-1.
// H_old for the epilogue lives in registers (thread's (row,ch) mapping is step-invariant).
__global__ __launch_bounds__(512, 2) void gru_scan(
    unsigned short* H0hiA, unsigned short* H0loA,
    unsigned short* H0hiB, unsigned short* H0loB,
    unsigned short* H1hiA, unsigned short* H1loA,
    unsigned short* H1hiB, unsigned short* H1loB,
    const unsigned short* __restrict__ FXhi,
    const unsigned short* __restrict__ FB0hi, const unsigned short* __restrict__ FB0lo,
    const unsigned short* __restrict__ FB1hi, const unsigned short* __restrict__ FB1lo,
    const float* __restrict__ bih0, const float* __restrict__ bhh0,
    const float* __restrict__ bih1, const float* __restrict__ bhh1,
    float* __restrict__ S1f, unsigned* bar, int* xslot)
{
    const int tid = threadIdx.x;
    int xcc;
    asm volatile("s_getreg_b32 %0, hwreg(HW_REG_XCC_ID)" : "=s"(xcc));
    xcc &= 7;
    __shared__ int sSlot;
    if (tid == 0) sSlot = atomicAdd(&xslot[xcc], 1) & 31;   // device-scope claim
    __syncthreads();
    const int slot = sSlot;           // 0..31 within this XCD
    const int mb2 = slot >> 4;        // row-half (128 rows) of the XCD's 256 rows
    const int cb = slot & 15;         // 16-ch tile within gate
    const int w = tid >> 6, lane = tid & 63;
    const int lay = w >> 2, wl = w & 3;
    const int l15 = lane & 15, q = lane >> 4;
    const int mt0 = xcc * 16 + mb2 * 8 + wl * 2;  // first 16-row tile (of 128)
    const int ntb = cb;
    unsigned* cnt = bar + (xcc * 2 + mb2) * 32;   // per-row-group counter, 128B apart

    // sB1: (hi+lo)[3][16*512] = 49152 shorts (96KB); sB0: (hi+lo)[3][10*512] = 30720 (60KB)
    __shared__ __align__(16) short sB[79872];
    short* sB1 = sB;
    short* sB0 = sB + 49152;
    stage_Bs<16, 512>(FB1hi, FB1lo, sB1, cb, tid);
    stage_Bs<10, 512>(FB0hi, FB0lo, sB0, cb, tid);
    __syncthreads();

    // per-thread epilogue constants (hoisted out of the scan loop)
    const float* bih = lay ? bih1 : bih0;
    const float* bhh = lay ? bhh1 : bhh0;
    const int c = (ntb << 4) + l15;   // channel 0..255
    const float brb = bih[c] + bhh[c];
    const float bzb = bih[256 + c] + bhh[256 + c];
    const float bni = bih[512 + c];
    const float bnh = bhh[512 + c];
    const int cfr = (c >> 5) * 512 + ((c >> 3) & 3) * 128 + (c & 7);

    // H_old registers: thread's 8 output elements, step-invariant mapping. H starts 0.
    float hreg[2][4];
#pragma unroll
    for (int mt = 0; mt < 2; ++mt)
#pragma unroll
        for (int rg = 0; rg < 4; ++rg) hreg[mt][rg] = 0.f;

    for (int i = 0; i <= TT; ++i) {
        const int p = i & 1;
        const unsigned short* H0r_hi = p ? H0hiB : H0hiA;
        const unsigned short* H0r_lo = p ? H0loB : H0loA;
        unsigned short*       H0w_hi = p ? H0hiA : H0hiB;
        unsigned short*       H0w_lo = p ? H0loA : H0loB;
        const unsigned short* H1r_hi = p ? H1hiB : H1hiA;
        const unsigned short* H1r_lo = p ? H1loB : H1loA;
        unsigned short*       H1w_hi = p ? H1hiA : H1hiB;
        unsigned short*       H1w_lo = p ? H1loA : H1loB;

        const bool active = lay ? (i >= 1) : (i < TT);
        if (active) {
            f32x4 ar[2], az[2], anh[2], anx[2];
#pragma unroll
            for (int j = 0; j < 2; ++j) {
                ar[j] = (f32x4){0.f,0.f,0.f,0.f}; az[j] = (f32x4){0.f,0.f,0.f,0.f};
                anh[j] = (f32x4){0.f,0.f,0.f,0.f}; anx[j] = (f32x4){0.f,0.f,0.f,0.f};
            }
            if (lay) {
                gru_core<16, true>(H1r_hi, H1r_lo, H0r_hi, H0r_lo, sB1,
                                   mt0, lane, ar, az, anh, anx);
            } else {
                gru_core<10, false>(H0r_hi, H0r_lo, FXhi + i * 131072,
                                    (const unsigned short*)0, sB0,
                                    mt0, lane, ar, az, anh, anx);
            }

            unsigned short* Whi = lay ? H1w_hi : H0w_hi;
            unsigned short* Wlo = lay ? H1w_lo : H0w_lo;

#pragma unroll
            for (int mt = 0; mt < 2; ++mt) {
                const int mtg = mt0 + mt;
                const int fbase = mtg * 4096 + cfr;
#pragma unroll
                for (int rg = 0; rg < 4; ++rg) {
                    const int mi = q * 4 + rg;
                    const int fidx = fbase + mi * 8;
                    const float rr = sigm(ar[mt][rg] + brb);
                    const float zz = sigm(az[mt][rg] + bzb);
                    const float nn = tanhfast(anx[mt][rg] + bni + rr * (anh[mt][rg] + bnh));
                    const float hn = (1.f - zz) * nn + zz * hreg[mt][rg];
                    const unsigned short hb = f2bf(hn);
                    const unsigned short lb = f2bf(hn - bf2f(hb));
                    Whi[fidx] = hb;
                    Wlo[fidx] = lb;
                    hreg[mt][rg] = bf2f(hb) + bf2f(lb);   // exact stored value
                    if (lay && i == TT) S1f[(mtg * 16 + mi) * 256 + c] = hn;
                }
            }
        }
        if (i < TT) xcd_bar(cnt, 16u * (unsigned)(i + 1));
    }
}

// ---------------- epilogue ----------------

__global__ __launch_bounds__(256) void proj_gemm(const float* __restrict__ S,
    const float* __restrict__ Wk, const float* __restrict__ bk,
    const float* __restrict__ Wv, const float* __restrict__ bv,
    const float* __restrict__ Wq, const float* __restrict__ bq,
    float* __restrict__ ok, float* __restrict__ ov, float* __restrict__ oq)
{
    __shared__ float sT[256][65];
    const int bid = blockIdx.x;            // 192 = 3p * 2h * 32lt
    const int p = bid >> 6;
    const int h = (bid >> 5) & 1;
    const int l0 = (bid & 31) * 64;
    const int tid = threadIdx.x;
    const float* W = (p == 0) ? Wk : ((p == 1) ? Wv : Wq);
    const float* b = (p == 0) ? bk : ((p == 1) ? bv : bq);
    float* o = (p == 0) ? ok : ((p == 1) ? ov : oq);

    for (int e = tid; e < 64 * 256; e += 256) {
        int k = e & 255, l = e >> 8;
        sT[k][l] = S[(l0 + l) * 256 + k];
    }
    __syncthreads();

    const int dg = tid & 15, lg = tid >> 4;
    const int d0 = dg * 8;
    const float* Wp = W + h * 32768 + d0;
    float acc[4][8];
#pragma unroll
    for (int i = 0; i < 4; ++i)
#pragma unroll
        for (int j = 0; j < 8; ++j) acc[i][j] = 0.f;

    for (int k = 0; k < 256; ++k) {
        f32x4 sv = *(const f32x4*)&sT[k][lg * 4];
        f32x4 w0 = *(const f32x4*)(Wp + k * 128);
        f32x4 w1 = *(const f32x4*)(Wp + k * 128 + 4);
#pragma unroll
        for (int i = 0; i < 4; ++i) {
#pragma unroll
            for (int j = 0; j < 4; ++j) {
                acc[i][j]     += sv[i] * w0[j];
                acc[i][4 + j] += sv[i] * w1[j];
            }
        }
    }
#pragma unroll
    for (int i = 0; i < 4; ++i) {
        float* op = o + (h * 2048 + l0 + lg * 4 + i) * 128 + d0;
#pragma unroll
        for (int j = 0; j < 8; ++j) op[j] = acc[i][j] + b[h * 128 + d0 + j];
    }
}

__global__ void proj3_kernel(const float* __restrict__ A, int M,
    const float* __restrict__ Wk, const float* __restrict__ bk,
    const float* __restrict__ Wv, const float* __restrict__ bv,
    float* __restrict__ ok, float* __restrict__ ov)
{
    int idx = blockIdx.x * 256 + threadIdx.x;
    if (idx >= 2 * 2 * M * 128) return;
    int d = idx & 127;
    int rest = idx >> 7;
    int l = rest % M;
    int ph = rest / M;
    int h = ph & 1, p = ph >> 1;
    const float* W = (p == 0) ? Wk : Wv;
    const float* b = (p == 0) ? bk : bv;
    float* o = (p == 0) ? ok : ov;
    float accv = b[h * 128 + d];
    const float* a = A + l * 256;
    const float* wp = W + h * (256 * 128) + d;
    for (int j = 0; j < 256; ++j) accv += a[j] * wp[j * 128];
    o[(h * M + l) * 128 + d] = accv;
}

__global__ void projR_kernel(const float* __restrict__ R,
    const float* __restrict__ Wq, const float* __restrict__ bq,
    float* __restrict__ oq)
{
    int idx = blockIdx.x * 256 + threadIdx.x;
    if (idx >= 2 * 30 * 128) return;
    int d = idx & 127;
    int rest = idx >> 7;
    int l = rest % 30;
    int h = rest / 30;
    float a = bq[h * 128 + d];
    const float* r = R + l * 256;
    const float* wp = Wq + h * 32768 + d;
    for (int j = 0; j < 256; ++j) a += r[j] * wp[j * 128];
    oq[(h * 30 + l) * 128 + d] = a;
}

__global__ void scores1_kernel(const float* __restrict__ qhR, const float* __restrict__ kh,
                               float* __restrict__ s1)
{
    int idx = blockIdx.x * 256 + threadIdx.x;
    if (idx >= 2 * 30 * 2048) return;
    int k = idx & 2047;
    int rest = idx >> 11;
    int i = rest % 30;
    int h = rest / 30;
    const f32x4* qp = (const f32x4*)(qhR + (h * 30 + i) * 128);
    const f32x4* kp = (const f32x4*)(kh + (h * 2048 + k) * 128);
    float acc = 0.f;
    for (int dd = 0; dd < 32; ++dd) {
        f32x4 a = qp[dd], b = kp[dd];
        acc += a[0] * b[0] + a[1] * b[1] + a[2] * b[2] + a[3] * b[3];
    }
    s1[idx] = acc * 0.08838834764831845f;
}

__global__ void softmax1_kernel(float* __restrict__ s1)
{
    __shared__ float red[256];
    float* p = s1 + blockIdx.x * 2048;
    int tid = threadIdx.x;
    float mx = -1e30f;
    for (int k = tid; k < 2048; k += 256) mx = fmaxf(mx, p[k]);
    red[tid] = mx; __syncthreads();
    for (int s = 128; s > 0; s >>= 1) { if (tid < s) red[tid] = fmaxf(red[tid], red[tid + s]); __syncthreads(); }
    mx = red[0]; __syncthreads();
    float sum = 0.f;
    for (int k = tid; k < 2048; k += 256) { float e = expf(p[k] - mx); p[k] = e; sum += e; }
    red[tid] = sum; __syncthreads();
    for (int s = 128; s > 0; s >>= 1) { if (tid < s) red[tid] += red[tid + s]; __syncthreads(); }
    float inv = 1.f / red[0];
    for (int k = tid; k < 2048; k += 256) p[k] *= inv;
}

// split-K o1: 16 k-slices per output row, fp32 atomicAdd into zeroed Bm.
__global__ void o1_kernel(const float* __restrict__ p1, const float* __restrict__ vh,
                          float* __restrict__ Bm)
{
    int bid = blockIdx.x;            // 60 rows * 16 k-slices
    int row = bid >> 4;              // h*30+i
    int ks = bid & 15;
    int h = row / 30;
    int i = row % 30;
    int d = threadIdx.x;             // 128
    const float* pp = p1 + row * 2048 + ks * 128;
    const float* vp = vh + (h * 2048 + ks * 128) * 128 + d;
    float acc = 0.f;
    for (int k = 0; k < 128; ++k) acc += pp[k] * vp[k * 128];
    atomicAdd(&Bm[i * 256 + h * 128 + d], acc);
}

__global__ __launch_bounds__(256) void attn2_kernel(
    const float* __restrict__ qh2, const float* __restrict__ kh2, const float* __restrict__ vh2,
    const float* __restrict__ S, const float* __restrict__ Wg,
    const float* __restrict__ bg, float* __restrict__ Smix)
{
    __shared__ float ks[2 * 30 * 129];
    __shared__ float qred[256];
    __shared__ float ps[64];
    int l = blockIdx.x;
    int tid = threadIdx.x;
    for (int idx = tid; idx < 2 * 30 * 128; idx += 256) {
        int hh = idx / 3840; int rem = idx - hh * 3840;
        int j = rem >> 7; int d = rem & 127;
        ks[(hh * 30 + j) * 129 + d] = kh2[idx];
    }
    int h = tid >> 7, d = tid & 127;
    qred[tid] = qh2[(h * 2048 + l) * 128 + d];
    __syncthreads();
    int w = tid >> 6, lane = tid & 63;
    if (w < 2 && lane < 32) {
        float sc = -1e30f;
        if (lane < 30) {
            const float* qp = qred + w * 128;
            float a = 0.f;
            for (int dd = 0; dd < 128; ++dd) a += qp[dd] * ks[(w * 30 + lane) * 129 + dd];
            sc = a * 0.08838834764831845f;
        }
        float mx = sc;
        for (int m = 16; m > 0; m >>= 1) mx = fmaxf(mx, __shfl_xor(mx, m, 32));
        float e = (lane < 30) ? expf(sc - mx) : 0.f;
        float sm = e;
        for (int m = 16; m > 0; m >>= 1) sm += __shfl_xor(sm, m, 32);
        ps[w * 32 + lane] = e / sm;
    }
    __syncthreads();
    float o = 0.f;
    const float* vp = vh2 + h * 3840 + d;
    for (int j = 0; j < 30; ++j) o += ps[h * 32 + j] * vp[j * 128];
    float sl = S[l * 256 + tid];
    qred[tid] = sl * Wg[tid];
    __syncthreads();
    for (int s = 128; s > 0; s >>= 1) { if (tid < s) qred[tid] += qred[tid + s]; __syncthreads(); }
    float alpha = 1.f / (1.f + expf(-(qred[0] + bg[0])));
    Smix[l * 256 + tid] = alpha * o + (1.f - alpha) * sl;
}

__global__ void w1t_kernel(const float* __restrict__ W1, float* __restrict__ W1T)
{
    int idx = blockIdx.x * 256 + threadIdx.x;  // 65536
    int j = idx & 255, c = idx >> 8;
    W1T[j * 256 + c] = W1[c * 256 + j];
}

__global__ void mlp_kernel(const float* __restrict__ Smix, const float* __restrict__ W1T,
                           const float* __restrict__ b1, float* __restrict__ S2)
{
    int idx = blockIdx.x * 256 + threadIdx.x;  // l*256+c
    int c = idx & 255; int l = idx >> 8;
    const float* a = Smix + l * 256;
    float acc = b1[c];
    for (int j = 0; j < 256; ++j) acc += a[j] * W1T[j * 256 + c];
    float v = fmaxf(acc, 0.f);
    S2[idx] = v + a[c];
}

__global__ void y_kernel(const float* __restrict__ S2, const float* __restrict__ W2,
                         const float* __restrict__ b2, float* __restrict__ y)
{
    __shared__ float red[256];
    int l = blockIdx.x; int tid = threadIdx.x;
    red[tid] = S2[l * 256 + tid] * W2[tid];
    __syncthreads();
    for (int s = 128; s > 0; s >>= 1) { if (tid < s) red[tid] += red[tid + s]; __syncthreads(); }
    if (tid == 0) y[l] = red[0] + b2[0];
}

__global__ void norm_kernel(const float* __restrict__ y, float* __restrict__ out)
{
    __shared__ float r1[1024], r2[1024];
    int tid = threadIdx.x;
    float s1v = 0.f, s2v = 0.f;
    for (int idx = tid; idx < 2048; idx += 1024) { float v = y[idx]; s1v += v; s2v += v * v; }
    r1[tid] = s1v; r2[tid] = s2v; __syncthreads();
    for (int s = 512; s > 0; s >>= 1) {
        if (tid < s) { r1[tid] += r1[tid + s]; r2[tid] += r2[tid + s]; }
        __syncthreads();
    }
    float mean = r1[0] / 2048.f;
    float var = fmaxf((r2[0] - 2048.f * mean * mean) / 2047.f, 0.f);
    float inv = 1.f / (sqrtf(var) + 1e-8f);
    for (int idx = tid; idx < 2048; idx += 1024)
        out[idx] = (y[idx] - mean) * inv;
}

extern "C" void kernel_launch(void* const* d_in, const int* in_sizes, int n_in,
                              void* d_out, int out_size, void* d_ws, size_t ws_size,
                              hipStream_t stream)
{
    const float* x    = (const float*)d_in[0];
    const float* Wih0 = (const float*)d_in[1];
    const float* Whh0 = (const float*)d_in[2];
    const float* bih0 = (const float*)d_in[3];
    const float* bhh0 = (const float*)d_in[4];
    const float* Wih1 = (const float*)d_in[5];
    const float* Whh1 = (const float*)d_in[6];
    const float* bih1 = (const float*)d_in[7];
    const float* bhh1 = (const float*)d_in[8];
    const float* Wq   = (const float*)d_in[9];
    const float* bq   = (const float*)d_in[10];
    const float* Wk   = (const float*)d_in[11];
    const float* bk   = (const float*)d_in[12];
    const float* Wv   = (const float*)d_in[13];
    const float* bv   = (const float*)d_in[14];
    const float* R    = (const float*)d_in[15];
    const float* Wg   = (const float*)d_in[16];
    const float* bg   = (const float*)d_in[17];
    const float* W1   = (const float*)d_in[18];
    const float* b1   = (const float*)d_in[19];
    const float* W2   = (const float*)d_in[20];
    const float* b2   = (const float*)d_in[21];

    float* ws = (float*)d_ws;
    size_t off = 0;
    auto alloc_f = [&](size_t n) { float* p = ws + off; off += n; return p; };
    float* S1f  = alloc_f(524288);
    float* kh   = alloc_f(524288);
    float* vh   = alloc_f(524288);
    float* qh2  = alloc_f(524288);
    float* qhR  = alloc_f(7680);
    float* s1   = alloc_f(122880);
    float* Bm   = alloc_f(7680);
    float* kh2  = alloc_f(7680);
    float* vh2  = alloc_f(7680);
    float* Smix = alloc_f(524288);
    float* S2   = alloc_f(524288);
    float* yv   = alloc_f(2048);
    float* W1T  = alloc_f(65536);
    unsigned short* us = (unsigned short*)(ws + off);
    size_t uoff = 0;
    auto alloc_u = [&](size_t n) { unsigned short* p = us + uoff; uoff += n; return p; };
    unsigned short* H0hi[2] = { alloc_u(524288), alloc_u(524288) };
    unsigned short* H0lo[2] = { alloc_u(524288), alloc_u(524288) };
    unsigned short* H1hi[2] = { alloc_u(524288), alloc_u(524288) };
    unsigned short* H1lo[2] = { alloc_u(524288), alloc_u(524288) };
    unsigned short* FB0hi = alloc_u(245760);
    unsigned short* FB0lo = alloc_u(245760);
    unsigned short* FB1hi = alloc_u(393216);
    unsigned short* FB1lo = alloc_u(393216);
    unsigned short* FXhi  = alloc_u(16777216);
    unsigned* barp = (unsigned*)alloc_u(1024);  // 512 u32: per-row-group counters at (x*2+g)*32
    int* xslotp = (int*)alloc_u(16);            // 8 ints: per-XCD slot claim

    pack_w<<<960, 256, 0, stream>>>(Whh0, Wih0, 64, 320, FB0hi, FB0lo, 245760);
    pack_w<<<1536, 256, 0, stream>>>(Whh1, Wih1, 256, 512, FB1hi, FB1lo, 393216);
    pack_x<<<65536, 256, 0, stream>>>(x, FXhi);
    (void)hipMemsetAsync(H0hi[0], 0, 1048576, stream);
    (void)hipMemsetAsync(H0lo[0], 0, 1048576, stream);
    (void)hipMemsetAsync(H1hi[1], 0, 1048576, stream);
    (void)hipMemsetAsync(H1lo[1], 0, 1048576, stream);
    (void)hipMemsetAsync(Bm, 0, 30720, stream);
    (void)hipMemsetAsync(barp, 0, 2048, stream);
    (void)hipMemsetAsync(xslotp, 0, 32, stream);

    gru_scan<<<256, 512, 0, stream>>>(
        H0hi[0], H0lo[0], H0hi[1], H0lo[1],
        H1hi[0], H1lo[0], H1hi[1], H1lo[1],
        FXhi, FB0hi, FB0lo, FB1hi, FB1lo,
        bih0, bhh0, bih1, bhh1, S1f, barp, xslotp);

    proj_gemm<<<192, 256, 0, stream>>>(S1f, Wk, bk, Wv, bv, Wq, bq, kh, vh, qh2);
    projR_kernel<<<30, 256, 0, stream>>>(R, Wq, bq, qhR);
    scores1_kernel<<<480, 256, 0, stream>>>(qhR, kh, s1);
    softmax1_kernel<<<60, 256, 0, stream>>>(s1);
    o1_kernel<<<960, 128, 0, stream>>>(s1, vh, Bm);
    proj3_kernel<<<60, 256, 0, stream>>>(Bm, 30, Wk, bk, Wv, bv, kh2, vh2);
    attn2_kernel<<<2048, 256, 0, stream>>>(qh2, kh2, vh2, S1f, Wg, bg, Smix);
    w1t_kernel<<<256, 256, 0, stream>>>(W1, W1T);
    mlp_kernel<<<2048, 256, 0, stream>>>(Smix, W1T, b1, S2);
    y_kernel<<<2048, 256, 0, stream>>>(S2, W2, b2, yv);
    norm_kernel<<<1, 1024, 0, stream>>>(yv, (float*)d_out);
}

// Round 7
// 1279.354 us; speedup vs baseline: 4.6261x; 1.3842x over previous
//
#include <hip/hip_runtime.h>
#include <hip/hip_bf16.h>

// CrossGRU round 12: r11 structure, atomic H-loads -> plain loads + per-step L1 inv.
// r11 stuck at 13.3us/step vs ~3-4us pipe floor. Diagnosis: ldH used agent-scope ATOMIC
// u64 loads (2 per 16B) -> serialized at the L2 atomic units (~25K atomic ops/XCD/step
// through 16 TCC channels ~ 6us), bypassing the streaming path. r12: plain dwordx4 H
// loads (L1-cacheable, half the instructions) + ONE buffer_inv (L1-only flash inv, no
// sc1 -> no L2 scan) per step inside the barrier. L1 is write-through so it never holds
// dirty data; pre-arrive syncthreads drains stores to the local L2. XCD-local partition,
// per-row-group barrier, all-B-in-LDS, registered H_old, raw gate math: unchanged.

#define HH  256
#define TT  128
#define INP 64
#define KH  8   // h-part kc count (256/32)

typedef float f32x4 __attribute__((ext_vector_type(4)));
typedef short bf16x8 __attribute__((ext_vector_type(8)));
typedef unsigned long long u64;

#define MFMA(A,B,C) __builtin_amdgcn_mfma_f32_16x16x32_bf16((A),(B),(C),0,0,0)

__device__ __forceinline__ float bf2f(unsigned short s) {
    unsigned u = ((unsigned)s) << 16;
    float f; __builtin_memcpy(&f, &u, 4); return f;
}
__device__ __forceinline__ unsigned short f2bf(float f) {
    unsigned u; __builtin_memcpy(&u, &f, 4);
    unsigned r = (u + 0x7FFFu + ((u >> 16) & 1u)) >> 16;
    return (unsigned short)r;
}

// raw-HW gate math: v_exp_f32 (2^x) + v_rcp_f32. ~1ulp err << bf16 rounding.
__device__ __forceinline__ float sigm(float x) {
    float t = __builtin_amdgcn_exp2f(x * -1.442695040889f);
    return __builtin_amdgcn_rcpf(1.f + t);
}
__device__ __forceinline__ float tanhfast(float x) {
    float xc = fminf(fmaxf(x, -15.f), 15.f);
    float t = __builtin_amdgcn_exp2f(xc * 2.885390081778f);
    return (t - 1.f) * __builtin_amdgcn_rcpf(t + 1.f);
}

// fragment-major index for element (row r, col k), K cols:
// idx = (r>>4)*(K*16) + (k>>5)*512 + ((k>>3)&3)*128 + (r&15)*8 + (k&7)

__global__ void pack_w(const float* __restrict__ Whh, const float* __restrict__ Wih,
                       int Kin, int Kw, unsigned short* __restrict__ FBhi,
                       unsigned short* __restrict__ FBlo, int total)
{
    int idx = blockIdx.x * 256 + threadIdx.x;
    if (idx >= total) return;
    int n = idx / Kw, k = idx - n * Kw;
    float v = (k < 256) ? Whh[n * 256 + k] : Wih[n * Kin + (k - 256)];
    int dst = (n >> 4) * (Kw * 16) + (k >> 5) * 512 + ((k >> 3) & 3) * 128 + (n & 15) * 8 + (k & 7);
    unsigned short h = f2bf(v);
    FBhi[dst] = h;
    FBlo[dst] = f2bf(v - bf2f(h));
}

__global__ void pack_x(const float* __restrict__ x, unsigned short* __restrict__ FXhi)
{
    int idx = blockIdx.x * 256 + threadIdx.x;  // 2048*128*64
    int k = idx & 63;
    int t = (idx >> 6) & 127;
    int m = idx >> 13;
    int dst = t * 131072 + (m >> 4) * 1024 + (k >> 5) * 512 + ((k >> 3) & 3) * 128 + (m & 15) * 8 + (k & 7);
    FXhi[dst] = f2bf(x[idx]);
}

// ---------------- B staging: global (frag-major, per-ntb slice) -> LDS ----------------
// LDS layout (shorts): Bhi[3][NKC*512] then Blo[3][NKC*512]
template<int NKC, int STRIDE>
__device__ __forceinline__ void stage_Bs(const unsigned short* __restrict__ Bhi,
                                         const unsigned short* __restrict__ Blo,
                                         short* __restrict__ sB, int ntb, int tid)
{
    const int Kw16 = NKC * 512;
#pragma unroll 1
    for (int t = tid; t < 3 * NKC * 64; t += STRIDE) {
        const int g = t / (NKC * 64);
        const int r = t - g * (NKC * 64);
        *(bf16x8*)(sB + g * Kw16 + r * 8) =
            *(const bf16x8*)(Bhi + (g * 16 + ntb) * Kw16 + r * 8);
        *(bf16x8*)(sB + 3 * Kw16 + g * Kw16 + r * 8) =
            *(const bf16x8*)(Blo + (g * 16 + ntb) * Kw16 + r * 8);
    }
}

// ---------------- GRU step core ----------------
// wave = 32 rows (2 m-tiles) x 16 ch (1 n-tile per gate), 3-term hi/lo MFMA.
// All B (hi+lo, all kc) from LDS, prefetched 2 kc ahead (ring of 3).
// A (plain dwordx4, L1-cached; freshness via per-step buffer_inv) prefetched 3 kc
// ahead (ring of 4). All ring indices static after full unroll.
template<int NKC, bool LAY>
__device__ __forceinline__ void gru_core(
    const unsigned short* Ah_h, const unsigned short* Al_h,
    const unsigned short* Ah_x, const unsigned short* Al_x,
    const short* __restrict__ sB, int mt0, int lane,
    f32x4 (&ar)[2], f32x4 (&az)[2], f32x4 (&anh)[2], f32x4 (&anx)[2])
{
    const int Kw16 = NKC * 512;            // Kw*16
    const int xs = LAY ? 4096 : 1024;      // x-source per-m-tile stride
    const int lo8 = lane * 8;
    const short* sH = sB + lo8;
    const short* sL = sB + 3 * Kw16 + lo8;

    bf16x8 A[4][2][2];                     // ring of 4
    bf16x8 B[3][3][2];                     // ring of 3: [slot][gate][hi/lo]

    auto ldA = [&](int kc, bf16x8 (&Ax)[2][2]) {
        if (kc < KH) {
#pragma unroll
            for (int mt = 0; mt < 2; ++mt) {
                Ax[mt][0] = *(const bf16x8*)(Ah_h + (mt0 + mt) * 4096 + kc * 512 + lo8);
                Ax[mt][1] = *(const bf16x8*)(Al_h + (mt0 + mt) * 4096 + kc * 512 + lo8);
            }
        } else {
#pragma unroll
            for (int mt = 0; mt < 2; ++mt) {
                Ax[mt][0] = *(const bf16x8*)(Ah_x + (mt0 + mt) * xs + (kc - KH) * 512 + lo8);
                if (LAY)
                    Ax[mt][1] = *(const bf16x8*)(Al_x + (mt0 + mt) * xs + (kc - KH) * 512 + lo8);
            }
        }
    };
    auto ldB = [&](int kc, bf16x8 (&Bx)[3][2]) {
#pragma unroll
        for (int g = 0; g < 3; ++g) {
            Bx[g][0] = *(const bf16x8*)(sH + g * Kw16 + kc * 512);
            Bx[g][1] = *(const bf16x8*)(sL + g * Kw16 + kc * 512);
        }
    };

    ldA(0, A[0]);
    if (NKC > 1) ldA(1, A[1]);
    if (NKC > 2) ldA(2, A[2]);
    ldB(0, B[0]);
    if (NKC > 1) ldB(1, B[1]);
#pragma unroll
    for (int kc = 0; kc < NKC; ++kc) {
        if (kc + 3 < NKC) ldA(kc + 3, A[(kc + 3) & 3]);
        if (kc + 2 < NKC) ldB(kc + 2, B[(kc + 2) % 3]);
        const bool hp = (kc < KH);
        const bool a3 = LAY || hp;     // 3rd (a_lo) term availability
        bf16x8 (&cA)[2][2] = A[kc & 3];
        bf16x8 (&cB)[3][2] = B[kc % 3];
#pragma unroll
        for (int mt = 0; mt < 2; ++mt) {
            ar[mt] = MFMA(cA[mt][0], cB[0][0], ar[mt]);
            ar[mt] = MFMA(cA[mt][0], cB[0][1], ar[mt]);
            if (a3) ar[mt] = MFMA(cA[mt][1], cB[0][0], ar[mt]);
            az[mt] = MFMA(cA[mt][0], cB[1][0], az[mt]);
            az[mt] = MFMA(cA[mt][0], cB[1][1], az[mt]);
            if (a3) az[mt] = MFMA(cA[mt][1], cB[1][0], az[mt]);
            if (hp) {
                anh[mt] = MFMA(cA[mt][0], cB[2][0], anh[mt]);
                anh[mt] = MFMA(cA[mt][0], cB[2][1], anh[mt]);
                if (a3) anh[mt] = MFMA(cA[mt][1], cB[2][0], anh[mt]);
            } else {
                anx[mt] = MFMA(cA[mt][0], cB[2][0], anx[mt]);
                anx[mt] = MFMA(cA[mt][0], cB[2][1], anx[mt]);
                if (a3) anx[mt] = MFMA(cA[mt][1], cB[2][0], anx[mt]);
            }
        }
    }
}

// Per-row-group barrier: 16 blocks on one counter. Stores drained to local L2 by the
// pre-arrive syncthreads (write-through L1). After the spin: buffer_inv = L1-only flash
// invalidate (no sc1 -> no L2 writeback/inv) so the next step's plain loads read fresh
// XCD-local L2 data. Counter spin stays atomic (must bypass L1).
__device__ __forceinline__ void xcd_bar(unsigned* cnt, unsigned need)
{
    __syncthreads();
    if (threadIdx.x == 0) {
        __hip_atomic_fetch_add(cnt, 1u, __ATOMIC_RELAXED, __HIP_MEMORY_SCOPE_AGENT);
        while (__hip_atomic_load(cnt, __ATOMIC_RELAXED, __HIP_MEMORY_SCOPE_AGENT) < need)
            __builtin_amdgcn_s_sleep(1);
    }
    __syncthreads();
    asm volatile("buffer_inv\n\ts_waitcnt vmcnt(0)" ::: "memory");
}

// Persistent scan: 256 blocks x 512 threads, 1 block/CU (156KB LDS) -> each XCD hosts
// exactly 32 blocks (pigeonhole). Block claims (row-half, ch-tile) within ITS OWN XCD.
// Sync group = 16 blocks sharing (xcc, row-half). Waves 0-3: L0 step i; 4-7: L1 step i-1.
// H_old for the epilogue lives in registers (thread's (row,ch) mapping is step-invariant).
__global__ __launch_bounds__(512, 2) void gru_scan(
    unsigned short* H0hiA, unsigned short* H0loA,
    unsigned short* H0hiB, unsigned short* H0loB,
    unsigned short* H1hiA, unsigned short* H1loA,
    unsigned short* H1hiB, unsigned short* H1loB,
    const unsigned short* __restrict__ FXhi,
    const unsigned short* __restrict__ FB0hi, const unsigned short* __restrict__ FB0lo,
    const unsigned short* __restrict__ FB1hi, const unsigned short* __restrict__ FB1lo,
    const float* __restrict__ bih0, const float* __restrict__ bhh0,
    const float* __restrict__ bih1, const float* __restrict__ bhh1,
    float* __restrict__ S1f, unsigned* bar, int* xslot)
{
    const int tid = threadIdx.x;
    int xcc;
    asm volatile("s_getreg_b32 %0, hwreg(HW_REG_XCC_ID)" : "=s"(xcc));
    xcc &= 7;
    __shared__ int sSlot;
    if (tid == 0) sSlot = atomicAdd(&xslot[xcc], 1) & 31;   // device-scope claim
    __syncthreads();
    const int slot = sSlot;           // 0..31 within this XCD
    const int mb2 = slot >> 4;        // row-half (128 rows) of the XCD's 256 rows
    const int cb = slot & 15;         // 16-ch tile within gate
    const int w = tid >> 6, lane = tid & 63;
    const int lay = w >> 2, wl = w & 3;
    const int l15 = lane & 15, q = lane >> 4;
    const int mt0 = xcc * 16 + mb2 * 8 + wl * 2;  // first 16-row tile (of 128)
    const int ntb = cb;
    unsigned* cnt = bar + (xcc * 2 + mb2) * 32;   // per-row-group counter, 128B apart

    // sB1: (hi+lo)[3][16*512] = 49152 shorts (96KB); sB0: (hi+lo)[3][10*512] = 30720 (60KB)
    __shared__ __align__(16) short sB[79872];
    short* sB1 = sB;
    short* sB0 = sB + 49152;
    stage_Bs<16, 512>(FB1hi, FB1lo, sB1, cb, tid);
    stage_Bs<10, 512>(FB0hi, FB0lo, sB0, cb, tid);
    __syncthreads();

    // per-thread epilogue constants (hoisted out of the scan loop)
    const float* bih = lay ? bih1 : bih0;
    const float* bhh = lay ? bhh1 : bhh0;
    const int c = (ntb << 4) + l15;   // channel 0..255
    const float brb = bih[c] + bhh[c];
    const float bzb = bih[256 + c] + bhh[256 + c];
    const float bni = bih[512 + c];
    const float bnh = bhh[512 + c];
    const int cfr = (c >> 5) * 512 + ((c >> 3) & 3) * 128 + (c & 7);

    // H_old registers: thread's 8 output elements, step-invariant mapping. H starts 0.
    float hreg[2][4];
#pragma unroll
    for (int mt = 0; mt < 2; ++mt)
#pragma unroll
        for (int rg = 0; rg < 4; ++rg) hreg[mt][rg] = 0.f;

    for (int i = 0; i <= TT; ++i) {
        const int p = i & 1;
        const unsigned short* H0r_hi = p ? H0hiB : H0hiA;
        const unsigned short* H0r_lo = p ? H0loB : H0loA;
        unsigned short*       H0w_hi = p ? H0hiA : H0hiB;
        unsigned short*       H0w_lo = p ? H0loA : H0loB;
        const unsigned short* H1r_hi = p ? H1hiB : H1hiA;
        const unsigned short* H1r_lo = p ? H1loB : H1loA;
        unsigned short*       H1w_hi = p ? H1hiA : H1hiB;
        unsigned short*       H1w_lo = p ? H1loA : H1loB;

        const bool active = lay ? (i >= 1) : (i < TT);
        if (active) {
            f32x4 ar[2], az[2], anh[2], anx[2];
#pragma unroll
            for (int j = 0; j < 2; ++j) {
                ar[j] = (f32x4){0.f,0.f,0.f,0.f}; az[j] = (f32x4){0.f,0.f,0.f,0.f};
                anh[j] = (f32x4){0.f,0.f,0.f,0.f}; anx[j] = (f32x4){0.f,0.f,0.f,0.f};
            }
            if (lay) {
                gru_core<16, true>(H1r_hi, H1r_lo, H0r_hi, H0r_lo, sB1,
                                   mt0, lane, ar, az, anh, anx);
            } else {
                gru_core<10, false>(H0r_hi, H0r_lo, FXhi + i * 131072,
                                    (const unsigned short*)0, sB0,
                                    mt0, lane, ar, az, anh, anx);
            }

            unsigned short* Whi = lay ? H1w_hi : H0w_hi;
            unsigned short* Wlo = lay ? H1w_lo : H0w_lo;

#pragma unroll
            for (int mt = 0; mt < 2; ++mt) {
                const int mtg = mt0 + mt;
                const int fbase = mtg * 4096 + cfr;
#pragma unroll
                for (int rg = 0; rg < 4; ++rg) {
                    const int mi = q * 4 + rg;
                    const int fidx = fbase + mi * 8;
                    const float rr = sigm(ar[mt][rg] + brb);
                    const float zz = sigm(az[mt][rg] + bzb);
                    const float nn = tanhfast(anx[mt][rg] + bni + rr * (anh[mt][rg] + bnh));
                    const float hn = (1.f - zz) * nn + zz * hreg[mt][rg];
                    const unsigned short hb = f2bf(hn);
                    const unsigned short lb = f2bf(hn - bf2f(hb));
                    Whi[fidx] = hb;
                    Wlo[fidx] = lb;
                    hreg[mt][rg] = bf2f(hb) + bf2f(lb);   // exact stored value
                    if (lay && i == TT) S1f[(mtg * 16 + mi) * 256 + c] = hn;
                }
            }
        }
        if (i < TT) xcd_bar(cnt, 16u * (unsigned)(i + 1));
    }
}

// ---------------- epilogue ----------------

__global__ __launch_bounds__(256) void proj_gemm(const float* __restrict__ S,
    const float* __restrict__ Wk, const float* __restrict__ bk,
    const float* __restrict__ Wv, const float* __restrict__ bv,
    const float* __restrict__ Wq, const float* __restrict__ bq,
    float* __restrict__ ok, float* __restrict__ ov, float* __restrict__ oq)
{
    __shared__ float sT[256][65];
    const int bid = blockIdx.x;            // 192 = 3p * 2h * 32lt
    const int p = bid >> 6;
    const int h = (bid >> 5) & 1;
    const int l0 = (bid & 31) * 64;
    const int tid = threadIdx.x;
    const float* W = (p == 0) ? Wk : ((p == 1) ? Wv : Wq);
    const float* b = (p == 0) ? bk : ((p == 1) ? bv : bq);
    float* o = (p == 0) ? ok : ((p == 1) ? ov : oq);

    for (int e = tid; e < 64 * 256; e += 256) {
        int k = e & 255, l = e >> 8;
        sT[k][l] = S[(l0 + l) * 256 + k];
    }
    __syncthreads();

    const int dg = tid & 15, lg = tid >> 4;
    const int d0 = dg * 8;
    const float* Wp = W + h * 32768 + d0;
    float acc[4][8];
#pragma unroll
    for (int i = 0; i < 4; ++i)
#pragma unroll
        for (int j = 0; j < 8; ++j) acc[i][j] = 0.f;

    for (int k = 0; k < 256; ++k) {
        f32x4 sv = *(const f32x4*)&sT[k][lg * 4];
        f32x4 w0 = *(const f32x4*)(Wp + k * 128);
        f32x4 w1 = *(const f32x4*)(Wp + k * 128 + 4);
#pragma unroll
        for (int i = 0; i < 4; ++i) {
#pragma unroll
            for (int j = 0; j < 4; ++j) {
                acc[i][j]     += sv[i] * w0[j];
                acc[i][4 + j] += sv[i] * w1[j];
            }
        }
    }
#pragma unroll
    for (int i = 0; i < 4; ++i) {
        float* op = o + (h * 2048 + l0 + lg * 4 + i) * 128 + d0;
#pragma unroll
        for (int j = 0; j < 8; ++j) op[j] = acc[i][j] + b[h * 128 + d0 + j];
    }
}

__global__ void proj3_kernel(const float* __restrict__ A, int M,
    const float* __restrict__ Wk, const float* __restrict__ bk,
    const float* __restrict__ Wv, const float* __restrict__ bv,
    float* __restrict__ ok, float* __restrict__ ov)
{
    int idx = blockIdx.x * 256 + threadIdx.x;
    if (idx >= 2 * 2 * M * 128) return;
    int d = idx & 127;
    int rest = idx >> 7;
    int l = rest % M;
    int ph = rest / M;
    int h = ph & 1, p = ph >> 1;
    const float* W = (p == 0) ? Wk : Wv;
    const float* b = (p == 0) ? bk : bv;
    float* o = (p == 0) ? ok : ov;
    float accv = b[h * 128 + d];
    const float* a = A + l * 256;
    const float* wp = W + h * (256 * 128) + d;
    for (int j = 0; j < 256; ++j) accv += a[j] * wp[j * 128];
    o[(h * M + l) * 128 + d] = accv;
}

__global__ void projR_kernel(const float* __restrict__ R,
    const float* __restrict__ Wq, const float* __restrict__ bq,
    float* __restrict__ oq)
{
    int idx = blockIdx.x * 256 + threadIdx.x;
    if (idx >= 2 * 30 * 128) return;
    int d = idx & 127;
    int rest = idx >> 7;
    int l = rest % 30;
    int h = rest / 30;
    float a = bq[h * 128 + d];
    const float* r = R + l * 256;
    const float* wp = Wq + h * 32768 + d;
    for (int j = 0; j < 256; ++j) a += r[j] * wp[j * 128];
    oq[(h * 30 + l) * 128 + d] = a;
}

__global__ void scores1_kernel(const float* __restrict__ qhR, const float* __restrict__ kh,
                               float* __restrict__ s1)
{
    int idx = blockIdx.x * 256 + threadIdx.x;
    if (idx >= 2 * 30 * 2048) return;
    int k = idx & 2047;
    int rest = idx >> 11;
    int i = rest % 30;
    int h = rest / 30;
    const f32x4* qp = (const f32x4*)(qhR + (h * 30 + i) * 128);
    const f32x4* kp = (const f32x4*)(kh + (h * 2048 + k) * 128);
    float acc = 0.f;
    for (int dd = 0; dd < 32; ++dd) {
        f32x4 a = qp[dd], b = kp[dd];
        acc += a[0] * b[0] + a[1] * b[1] + a[2] * b[2] + a[3] * b[3];
    }
    s1[idx] = acc * 0.08838834764831845f;
}

__global__ void softmax1_kernel(float* __restrict__ s1)
{
    __shared__ float red[256];
    float* p = s1 + blockIdx.x * 2048;
    int tid = threadIdx.x;
    float mx = -1e30f;
    for (int k = tid; k < 2048; k += 256) mx = fmaxf(mx, p[k]);
    red[tid] = mx; __syncthreads();
    for (int s = 128; s > 0; s >>= 1) { if (tid < s) red[tid] = fmaxf(red[tid], red[tid + s]); __syncthreads(); }
    mx = red[0]; __syncthreads();
    float sum = 0.f;
    for (int k = tid; k < 2048; k += 256) { float e = expf(p[k] - mx); p[k] = e; sum += e; }
    red[tid] = sum; __syncthreads();
    for (int s = 128; s > 0; s >>= 1) { if (tid < s) red[tid] += red[tid + s]; __syncthreads(); }
    float inv = 1.f / red[0];
    for (int k = tid; k < 2048; k += 256) p[k] *= inv;
}

// split-K o1: 16 k-slices per output row, fp32 atomicAdd into zeroed Bm.
__global__ void o1_kernel(const float* __restrict__ p1, const float* __restrict__ vh,
                          float* __restrict__ Bm)
{
    int bid = blockIdx.x;            // 60 rows * 16 k-slices
    int row = bid >> 4;              // h*30+i
    int ks = bid & 15;
    int h = row / 30;
    int i = row % 30;
    int d = threadIdx.x;             // 128
    const float* pp = p1 + row * 2048 + ks * 128;
    const float* vp = vh + (h * 2048 + ks * 128) * 128 + d;
    float acc = 0.f;
    for (int k = 0; k < 128; ++k) acc += pp[k] * vp[k * 128];
    atomicAdd(&Bm[i * 256 + h * 128 + d], acc);
}

__global__ __launch_bounds__(256) void attn2_kernel(
    const float* __restrict__ qh2, const float* __restrict__ kh2, const float* __restrict__ vh2,
    const float* __restrict__ S, const float* __restrict__ Wg,
    const float* __restrict__ bg, float* __restrict__ Smix)
{
    __shared__ float ks[2 * 30 * 129];
    __shared__ float qred[256];
    __shared__ float ps[64];
    int l = blockIdx.x;
    int tid = threadIdx.x;
    for (int idx = tid; idx < 2 * 30 * 128; idx += 256) {
        int hh = idx / 3840; int rem = idx - hh * 3840;
        int j = rem >> 7; int d = rem & 127;
        ks[(hh * 30 + j) * 129 + d] = kh2[idx];
    }
    int h = tid >> 7, d = tid & 127;
    qred[tid] = qh2[(h * 2048 + l) * 128 + d];
    __syncthreads();
    int w = tid >> 6, lane = tid & 63;
    if (w < 2 && lane < 32) {
        float sc = -1e30f;
        if (lane < 30) {
            const float* qp = qred + w * 128;
            float a = 0.f;
            for (int dd = 0; dd < 128; ++dd) a += qp[dd] * ks[(w * 30 + lane) * 129 + dd];
            sc = a * 0.08838834764831845f;
        }
        float mx = sc;
        for (int m = 16; m > 0; m >>= 1) mx = fmaxf(mx, __shfl_xor(mx, m, 32));
        float e = (lane < 30) ? expf(sc - mx) : 0.f;
        float sm = e;
        for (int m = 16; m > 0; m >>= 1) sm += __shfl_xor(sm, m, 32);
        ps[w * 32 + lane] = e / sm;
    }
    __syncthreads();
    float o = 0.f;
    const float* vp = vh2 + h * 3840 + d;
    for (int j = 0; j < 30; ++j) o += ps[h * 32 + j] * vp[j * 128];
    float sl = S[l * 256 + tid];
    qred[tid] = sl * Wg[tid];
    __syncthreads();
    for (int s = 128; s > 0; s >>= 1) { if (tid < s) qred[tid] += qred[tid + s]; __syncthreads(); }
    float alpha = 1.f / (1.f + expf(-(qred[0] + bg[0])));
    Smix[l * 256 + tid] = alpha * o + (1.f - alpha) * sl;
}

__global__ void w1t_kernel(const float* __restrict__ W1, float* __restrict__ W1T)
{
    int idx = blockIdx.x * 256 + threadIdx.x;  // 65536
    int j = idx & 255, c = idx >> 8;
    W1T[j * 256 + c] = W1[c * 256 + j];
}

__global__ void mlp_kernel(const float* __restrict__ Smix, const float* __restrict__ W1T,
                           const float* __restrict__ b1, float* __restrict__ S2)
{
    int idx = blockIdx.x * 256 + threadIdx.x;  // l*256+c
    int c = idx & 255; int l = idx >> 8;
    const float* a = Smix + l * 256;
    float acc = b1[c];
    for (int j = 0; j < 256; ++j) acc += a[j] * W1T[j * 256 + c];
    float v = fmaxf(acc, 0.f);
    S2[idx] = v + a[c];
}

__global__ void y_kernel(const float* __restrict__ S2, const float* __restrict__ W2,
                         const float* __restrict__ b2, float* __restrict__ y)
{
    __shared__ float red[256];
    int l = blockIdx.x; int tid = threadIdx.x;
    red[tid] = S2[l * 256 + tid] * W2[tid];
    __syncthreads();
    for (int s = 128; s > 0; s >>= 1) { if (tid < s) red[tid] += red[tid + s]; __syncthreads(); }
    if (tid == 0) y[l] = red[0] + b2[0];
}

__global__ void norm_kernel(const float* __restrict__ y, float* __restrict__ out)
{
    __shared__ float r1[1024], r2[1024];
    int tid = threadIdx.x;
    float s1v = 0.f, s2v = 0.f;
    for (int idx = tid; idx < 2048; idx += 1024) { float v = y[idx]; s1v += v; s2v += v * v; }
    r1[tid] = s1v; r2[tid] = s2v; __syncthreads();
    for (int s = 512; s > 0; s >>= 1) {
        if (tid < s) { r1[tid] += r1[tid + s]; r2[tid] += r2[tid + s]; }
        __syncthreads();
    }
    float mean = r1[0] / 2048.f;
    float var = fmaxf((r2[0] - 2048.f * mean * mean) / 2047.f, 0.f);
    float inv = 1.f / (sqrtf(var) + 1e-8f);
    for (int idx = tid; idx < 2048; idx += 1024)
        out[idx] = (y[idx] - mean) * inv;
}

extern "C" void kernel_launch(void* const* d_in, const int* in_sizes, int n_in,
                              void* d_out, int out_size, void* d_ws, size_t ws_size,
                              hipStream_t stream)
{
    const float* x    = (const float*)d_in[0];
    const float* Wih0 = (const float*)d_in[1];
    const float* Whh0 = (const float*)d_in[2];
    const float* bih0 = (const float*)d_in[3];
    const float* bhh0 = (const float*)d_in[4];
    const float* Wih1 = (const float*)d_in[5];
    const float* Whh1 = (const float*)d_in[6];
    const float* bih1 = (const float*)d_in[7];
    const float* bhh1 = (const float*)d_in[8];
    const float* Wq   = (const float*)d_in[9];
    const float* bq   = (const float*)d_in[10];
    const float* Wk   = (const float*)d_in[11];
    const float* bk   = (const float*)d_in[12];
    const float* Wv   = (const float*)d_in[13];
    const float* bv   = (const float*)d_in[14];
    const float* R    = (const float*)d_in[15];
    const float* Wg   = (const float*)d_in[16];
    const float* bg   = (const float*)d_in[17];
    const float* W1   = (const float*)d_in[18];
    const float* b1   = (const float*)d_in[19];
    const float* W2   = (const float*)d_in[20];
    const float* b2   = (const float*)d_in[21];

    float* ws = (float*)d_ws;
    size_t off = 0;
    auto alloc_f = [&](size_t n) { float* p = ws + off; off += n; return p; };
    float* S1f  = alloc_f(524288);
    float* kh   = alloc_f(524288);
    float* vh   = alloc_f(524288);
    float* qh2  = alloc_f(524288);
    float* qhR  = alloc_f(7680);
    float* s1   = alloc_f(122880);
    float* Bm   = alloc_f(7680);
    float* kh2  = alloc_f(7680);
    float* vh2  = alloc_f(7680);
    float* Smix = alloc_f(524288);
    float* S2   = alloc_f(524288);
    float* yv   = alloc_f(2048);
    float* W1T  = alloc_f(65536);
    unsigned short* us = (unsigned short*)(ws + off);
    size_t uoff = 0;
    auto alloc_u = [&](size_t n) { unsigned short* p = us + uoff; uoff += n; return p; };
    unsigned short* H0hi[2] = { alloc_u(524288), alloc_u(524288) };
    unsigned short* H0lo[2] = { alloc_u(524288), alloc_u(524288) };
    unsigned short* H1hi[2] = { alloc_u(524288), alloc_u(524288) };
    unsigned short* H1lo[2] = { alloc_u(524288), alloc_u(524288) };
    unsigned short* FB0hi = alloc_u(245760);
    unsigned short* FB0lo = alloc_u(245760);
    unsigned short* FB1hi = alloc_u(393216);
    unsigned short* FB1lo = alloc_u(393216);
    unsigned short* FXhi  = alloc_u(16777216);
    unsigned* barp = (unsigned*)alloc_u(1024);  // 512 u32: per-row-group counters at (x*2+g)*32
    int* xslotp = (int*)alloc_u(16);            // 8 ints: per-XCD slot claim

    pack_w<<<960, 256, 0, stream>>>(Whh0, Wih0, 64, 320, FB0hi, FB0lo, 245760);
    pack_w<<<1536, 256, 0, stream>>>(Whh1, Wih1, 256, 512, FB1hi, FB1lo, 393216);
    pack_x<<<65536, 256, 0, stream>>>(x, FXhi);
    (void)hipMemsetAsync(H0hi[0], 0, 1048576, stream);
    (void)hipMemsetAsync(H0lo[0], 0, 1048576, stream);
    (void)hipMemsetAsync(H1hi[1], 0, 1048576, stream);
    (void)hipMemsetAsync(H1lo[1], 0, 1048576, stream);
    (void)hipMemsetAsync(Bm, 0, 30720, stream);
    (void)hipMemsetAsync(barp, 0, 2048, stream);
    (void)hipMemsetAsync(xslotp, 0, 32, stream);

    gru_scan<<<256, 512, 0, stream>>>(
        H0hi[0], H0lo[0], H0hi[1], H0lo[1],
        H1hi[0], H1lo[0], H1hi[1], H1lo[1],
        FXhi, FB0hi, FB0lo, FB1hi, FB1lo,
        bih0, bhh0, bih1, bhh1, S1f, barp, xslotp);

    proj_gemm<<<192, 256, 0, stream>>>(S1f, Wk, bk, Wv, bv, Wq, bq, kh, vh, qh2);
    projR_kernel<<<30, 256, 0, stream>>>(R, Wq, bq, qhR);
    scores1_kernel<<<480, 256, 0, stream>>>(qhR, kh, s1);
    softmax1_kernel<<<60, 256, 0, stream>>>(s1);
    o1_kernel<<<960, 128, 0, stream>>>(s1, vh, Bm);
    proj3_kernel<<<60, 256, 0, stream>>>(Bm, 30, Wk, bk, Wv, bv, kh2, vh2);
    attn2_kernel<<<2048, 256, 0, stream>>>(qh2, kh2, vh2, S1f, Wg, bg, Smix);
    w1t_kernel<<<256, 256, 0, stream>>>(W1, W1T);
    mlp_kernel<<<2048, 256, 0, stream>>>(Smix, W1T, b1, S2);
    y_kernel<<<2048, 256, 0, stream>>>(S2, W2, b2, yv);
    norm_kernel<<<1, 1024, 0, stream>>>(yv, (float*)d_out);
}